// Round 14
// baseline (319.570 us; speedup 1.0000x reference)
//
#include <hip/hip_runtime.h>

typedef __attribute__((ext_vector_type(4))) float f32x4;
typedef __attribute__((ext_vector_type(8))) short bf16x8;
typedef __attribute__((ext_vector_type(4))) unsigned int u32x4;

static __device__ __forceinline__ short f2bf(float f){
    unsigned int u = __builtin_bit_cast(unsigned int, f);
    unsigned int r = (u + 0x7fffu + ((u >> 16) & 1u)) >> 16;
    return (short)r;
}
static __device__ __forceinline__ void gload_lds16(const void* g, void* l){
    __builtin_amdgcn_global_load_lds((const __attribute__((address_space(1))) void*)g,
                                     (__attribute__((address_space(3))) void*)l, 16, 0, 0);
}
static __device__ __forceinline__ float exp2fast(float x){
    float r; asm("v_exp_f32 %0, %1" : "=v"(r) : "v"(x)); return r;
}
static __device__ __forceinline__ unsigned int packbf(float lo, float hi){
#if __has_builtin(__builtin_amdgcn_perm)
    return __builtin_amdgcn_perm(__builtin_bit_cast(unsigned int, hi),
                                 __builtin_bit_cast(unsigned int, lo), 0x07060302u);
#else
    return (__builtin_bit_cast(unsigned int, hi) & 0xffff0000u) |
           (__builtin_bit_cast(unsigned int, lo) >> 16);
#endif
}
static __device__ __forceinline__ void prio_hi(){
#if defined(__HIP_DEVICE_COMPILE__)
    __builtin_amdgcn_s_setprio(1);
#endif
}
static __device__ __forceinline__ void prio_lo(){
#if defined(__HIP_DEVICE_COMPILE__)
    __builtin_amdgcn_s_setprio(0);
#endif
}
static __device__ __forceinline__ void barrier_raw(){
#if defined(__HIP_DEVICE_COMPILE__)
    __builtin_amdgcn_s_barrier();
#endif
}

// ---------------- fused prep: casts + mask bias + bias combine + weight transposes ----------------
static __device__ __forceinline__ void transcast_body(const float* __restrict__ w,
                                                      short* __restrict__ wT,
                                                      int K, int N, int bx, int by, int t){
    int n = bx * 256 + t;
    int k0 = by * 8;
    bf16x8 o;
#pragma unroll
    for (int j = 0; j < 8; j++) o[j] = f2bf(w[(long)(k0 + j) * N + n]);
    *(bf16x8*)(wT + (long)n * K + k0) = o;
}
// TOTAL blocks = 12288 + 32 + 64 + 4 + 2368 = 14756.
__global__ __launch_bounds__(256) void prep_weights(
    const float* __restrict__ queries, const float* __restrict__ box,
    const float* __restrict__ ctr, const float* __restrict__ kvd, const float* __restrict__ kvp,
    const unsigned char* __restrict__ qmask, const unsigned char* __restrict__ kmask,
    const float* __restrict__ b_qkv, const float* __restrict__ b_pos,
    short* __restrict__ Xcat, short* __restrict__ ctr_bf,
    short* __restrict__ kvd_bf, short* __restrict__ kvp_bf,
    float* __restrict__ mb_sa, float* __restrict__ mb_ca, float* __restrict__ bcomb,
    const float* __restrict__ w_qkv, const float* __restrict__ w_pos,
    const float* __restrict__ w_caq, const float* __restrict__ w_cakv,
    const float* __restrict__ w_caqp, const float* __restrict__ w_cakp,
    const float* __restrict__ w_f1, const float* __restrict__ w_f2,
    short* __restrict__ wTm_qk, short* __restrict__ wTv,
    short* __restrict__ wT_caq, short* __restrict__ wT_cakv,
    short* __restrict__ wT_caqp, short* __restrict__ wT_cakp,
    short* __restrict__ wT_f1, short* __restrict__ wT_f2)
{
    int bb = blockIdx.x, t = threadIdx.x;
    if (bb < 12288){
        const float* src; short* dst; long i; long stride; int logRow; int colOff;
        if (bb < 2048){ src = queries; dst = Xcat; i = ((long)bb * 256 + t) * 8; logRow = 9;  stride = 1536; colOff = 0; }
        else if (bb < 6144){ src = box; dst = Xcat; i = ((long)(bb - 2048) * 256 + t) * 8; logRow = 10; stride = 1536; colOff = 512; }
        else if (bb < 8192){ src = ctr; dst = ctr_bf; i = ((long)(bb - 6144) * 256 + t) * 8; logRow = 0; stride = 0; colOff = 0; }
        else if (bb < 10240){ src = kvd; dst = kvd_bf; i = ((long)(bb - 8192) * 256 + t) * 8; logRow = 0; stride = 0; colOff = 0; }
        else { src = kvp; dst = kvp_bf; i = ((long)(bb - 10240) * 256 + t) * 8; logRow = 0; stride = 0; colOff = 0; }
        f32x4 a = *(const f32x4*)(src + i);
        f32x4 b = *(const f32x4*)(src + i + 4);
        bf16x8 o;
#pragma unroll
        for (int j = 0; j < 4; j++){ o[j] = f2bf(a[j]); o[4 + j] = f2bf(b[j]); }
        long oi = logRow ? ((i >> logRow) * stride + colOff + (i & ((1L << logRow) - 1))) : i;
        *(bf16x8*)(dst + oi) = o;
        return;
    }
    if (bb < 12320){ int i = (bb - 12288) * 256 + t; mb_sa[i] = qmask[i] ? -1e30f : 0.f; return; }
    if (bb < 12384){ int i = (bb - 12320) * 256 + t; mb_ca[i] = kmask[i] ? -1e30f : 0.f; return; }
    if (bb < 12388){ int i = (bb - 12384) * 256 + t; if (i < 1024) bcomb[i] = b_qkv[i] + b_pos[i]; return; }
    int wb = bb - 12388;
    if (wb < 768){
        int by = wb / 4, bx = wb % 4;
        int n = bx * 256 + t;
        int k0 = by * 8;
        bf16x8 o;
#pragma unroll
        for (int j = 0; j < 8; j++){
            int kk = k0 + j;
            float v = (kk < 512) ? w_qkv[(long)kk * 1536 + n] : w_pos[(long)(kk - 512) * 1024 + n];
            o[j] = f2bf(v);
        }
        *(bf16x8*)(wTm_qk + (long)n * 1536 + k0) = o;
    }
    else if (wb < 896){
        int lb = wb - 768;
        int by = lb / 2, bx = lb % 2;
        int n = bx * 256 + t;
        int k0 = by * 8;
        bf16x8 o;
#pragma unroll
        for (int j = 0; j < 8; j++) o[j] = f2bf(w_qkv[(long)(k0 + j) * 1536 + 1024 + n]);
        *(bf16x8*)(wTv + (long)n * 512 + k0) = o;
    }
    else if (wb < 1024){ int lb = wb - 896;  transcast_body(w_caq,  wT_caq,  512, 512,  lb % 2, lb / 2, t); }
    else if (wb < 1152){ int lb = wb - 1024; transcast_body(w_cakv, wT_cakv, 256, 1024, lb % 4, lb / 4, t); }
    else if (wb < 1280){ int lb = wb - 1152; transcast_body(w_caqp, wT_caqp, 512, 512,  lb % 2, lb / 2, t); }
    else if (wb < 1344){ int lb = wb - 1280; transcast_body(w_cakp, wT_cakp, 256, 512,  lb % 2, lb / 2, t); }
    else if (wb < 1856){ int lb = wb - 1344; transcast_body(w_f1,   wT_f1,   512, 2048, lb % 8, lb / 8, t); }
    else               { int lb = wb - 1856; transcast_body(w_f2,   wT_f2,   2048, 512, lb % 2, lb / 2, t); }
}

// ---------------- multi-segment GEMM (counted-vmcnt pipeline) ----------------
// Uniform tile: BN=64, 128 threads, 2 waves x (64x64). Up to 6 independent GEMMs per
// launch. 3-deep gload_lds staging with counted vmcnt (never 0 in steady state) and
// raw barriers (T3/T4): per iter {issue stage(k+2); vmcnt(12); barrier; ds_read+MFMA;
// lgkmcnt(0); barrier}. flags: 1=relu; 2=headsplit; 4=Vt-transpose for cols>=vtColBase.
struct GD {
    const short* A; const short* Bt; const float* bias;
    short* Cbf; float* Cf; short* Vt;
    long lda;
    int N, K, flags, vtColBase, snShift, vtSN, blkStart, nbx, nblk;
};
struct GD6 { GD g[6]; int n; };

__global__ __launch_bounds__(128, 2) void gemm_multi(GD6 dd)
{
    constexpr int BN = 64, BLOCK = 128;
    constexpr int BUF = (128 + BN) * 32;      // shorts per buffer (12KB)
    constexpr int EST = BN + 4;
    __shared__ __attribute__((aligned(16))) char smem[3 * BUF * 2];
    float* lC = (float*)smem;
    int bb = blockIdx.x;
    int si = 0;
#pragma unroll
    for (int i = 1; i < 6; i++) if (i < dd.n && bb >= dd.g[i].blkStart) si = i;
    const short* A = dd.g[si].A;
    const short* Bt = dd.g[si].Bt;
    const float* bias = dd.g[si].bias;
    short* Cbf = dd.g[si].Cbf;
    float* Cf = dd.g[si].Cf;
    short* Vt = dd.g[si].Vt;
    long lda = dd.g[si].lda;
    int N = dd.g[si].N, K = dd.g[si].K, flags = dd.g[si].flags;
    int vtColBase = dd.g[si].vtColBase, snShift = dd.g[si].snShift, vtSN = dd.g[si].vtSN;
    int nbx = dd.g[si].nbx, nblk = dd.g[si].nblk;

    int t = threadIdx.x, w = t >> 6, l = t & 63;
    int cl = l & 15, g = l >> 4;
    int flat = bb - dd.g[si].blkStart;
    int q8 = nblk >> 3;
    int swz = (flat & 7) * q8 + (flat >> 3);
    long r0 = (long)(swz / nbx) * 128, c0 = (long)(swz % nbx) * BN;
    int wr = w;
    f32x4 acc[4][4];
#pragma unroll
    for (int mi = 0; mi < 4; mi++)
#pragma unroll
        for (int ni = 0; ni < 4; ni++) acc[mi][ni] = f32x4{0.f, 0.f, 0.f, 0.f};

    auto stage = [&](int d, int k0){
        char* lA = smem + (size_t)d * BUF * 2;
        char* lB = lA + 128 * 32 * 2;
#pragma unroll
        for (int i = 0; i < 4; i++){
            int s = i * BLOCK + t;
            int row = s >> 2, blk = s & 3;
            int sb = blk ^ (row & 3);
            gload_lds16(A + (r0 + row) * lda + k0 + sb * 8, lA + i * (BLOCK * 16) + w * 1024);
        }
#pragma unroll
        for (int i = 0; i < 2; i++){
            int s = i * BLOCK + t;
            int row = s >> 2, blk = s & 3;
            int sb = blk ^ (row & 3);
            gload_lds16(Bt + (c0 + row) * (long)K + k0 + sb * 8, lB + i * (BLOCK * 16) + w * 1024);
        }
    };

    int NK = K / 32;
    stage(0, 0);
    stage(1, 32);
    int bc = 0, bs = 2;
    for (int kt = 0; kt < NK; kt++){
        if (kt + 2 < NK){
            stage(bs, (kt + 2) * 32);
            bs = (bs == 2) ? 0 : bs + 1;
            asm volatile("s_waitcnt vmcnt(12)" ::: "memory");
        } else if (kt + 1 < NK){
            asm volatile("s_waitcnt vmcnt(6)" ::: "memory");
        } else {
            asm volatile("s_waitcnt vmcnt(0)" ::: "memory");
        }
        barrier_raw();                       // all waves' tile-kt loads landed
        const short* lA = (const short*)(smem + (size_t)bc * BUF * 2);
        const short* lB = lA + 128 * 32;
        bf16x8 af[4], bfr[4];
#pragma unroll
        for (int mi = 0; mi < 4; mi++){
            int row = wr * 64 + mi * 16 + cl;
            af[mi] = *(const bf16x8*)(lA + row * 32 + (g ^ (row & 3)) * 8);
        }
#pragma unroll
        for (int ni = 0; ni < 4; ni++){
            int row = ni * 16 + cl;
            bfr[ni] = *(const bf16x8*)(lB + row * 32 + (g ^ (row & 3)) * 8);
        }
        prio_hi();
#pragma unroll
        for (int mi = 0; mi < 4; mi++)
#pragma unroll
            for (int ni = 0; ni < 4; ni++)
                acc[mi][ni] = __builtin_amdgcn_mfma_f32_16x16x32_bf16(af[mi], bfr[ni], acc[mi][ni], 0, 0, 0);
        prio_lo();
        asm volatile("s_waitcnt lgkmcnt(0)" ::: "memory");
        barrier_raw();                       // reads of tile kt done; buffer reusable
        bc = (bc == 2) ? 0 : bc + 1;
    }

    bool vtBlock = (flags & 4) && (c0 >= vtColBase);
#pragma unroll
    for (int mi = 0; mi < 4; mi++){
        __syncthreads();
#pragma unroll
        for (int ni = 0; ni < 4; ni++)
#pragma unroll
            for (int rr = 0; rr < 4; rr++)
                lC[(wr * 16 + g * 4 + rr) * EST + ni * 16 + cl] = acc[mi][ni][rr];
        __syncthreads();
        if (vtBlock){
#pragma unroll
            for (int c2 = 0; c2 < 2; c2++){
                int task = t + BLOCK * c2;
                int col = task & 63;
                int wrg = (task >> 6) & 1;
                int ch = task >> 7;
                float bv = bias[c0 + col];
                long qg0 = r0 + wrg * 64 + mi * 16 + ch * 8;
                bf16x8 ob;
#pragma unroll
                for (int j = 0; j < 8; j++)
                    ob[j] = f2bf(lC[(wrg * 16 + ch * 8 + j) * EST + col] + bv);
                long dvg = c0 - vtColBase + col;
                long h = dvg >> 6, dvv = dvg & 63;
                long b = qg0 >> snShift;
                long loc = qg0 & ((1L << snShift) - 1);
                *(bf16x8*)(Vt + ((b * 8 + h) * 64 + dvv) * (long)vtSN + loc) = ob;
            }
        } else {
#pragma unroll
            for (int c2 = 0; c2 < 2; c2++){
                int chunk = t + BLOCK * c2;
                int row = chunk >> 3;
                int coloff = (chunk & 7) * 8;
                long grow = r0 + (row >> 4) * 64 + mi * 16 + (row & 15);
                long gcol = c0 + coloff;
                f32x4 bv0 = *(const f32x4*)(bias + gcol);
                f32x4 bv1 = *(const f32x4*)(bias + gcol + 4);
                float v[8];
#pragma unroll
                for (int j = 0; j < 8; j++){
                    float x = lC[row * EST + coloff + j] + (j < 4 ? bv0[j] : bv1[j - 4]);
                    if (flags & 1) x = fmaxf(x, 0.f);
                    v[j] = x;
                }
                if (Cf){
                    *(f32x4*)(Cf + grow * N + gcol) = f32x4{v[0], v[1], v[2], v[3]};
                    *(f32x4*)(Cf + grow * N + gcol + 4) = f32x4{v[4], v[5], v[6], v[7]};
                } else {
                    bf16x8 ob;
#pragma unroll
                    for (int j = 0; j < 8; j++) ob[j] = f2bf(v[j]);
                    long idx;
                    if (flags & 2){
                        long part = gcol >> 9;
                        long cc = gcol & 511;
                        long b = grow >> 10, qn = grow & 1023;
                        long h = cc >> 6, d = cc & 63;
                        idx = ((part * 64 + b * 8 + h) * 1024 + qn) * 64 + d;
                    } else if (flags & 4){
                        idx = grow * (long)vtColBase + gcol;
                    } else {
                        idx = grow * N + gcol;
                    }
                    *(bf16x8*)(Cbf + idx) = ob;
                }
            }
        }
    }
}

// ---------------- fused residual + LayerNorm (512 cols), wave-per-row ----------------
__global__ __launch_bounds__(256) void ln_fuse(const float* __restrict__ a, const float* __restrict__ b,
                                               const float* __restrict__ g, const float* __restrict__ be,
                                               float* __restrict__ outf, short* __restrict__ outb){
    int w = threadIdx.x >> 6, l = threadIdx.x & 63;
    long row = (long)blockIdx.x * 4 + w;
    long base = row * 512 + l * 8;
    f32x4 a0 = *(const f32x4*)(a + base);
    f32x4 a1 = *(const f32x4*)(a + base + 4);
    f32x4 b0 = *(const f32x4*)(b + base);
    f32x4 b1 = *(const f32x4*)(b + base + 4);
    float x[8]; float s = 0.f, s2 = 0.f;
#pragma unroll
    for (int j = 0; j < 4; j++){ x[j] = a0[j] + b0[j]; x[4 + j] = a1[j] + b1[j]; }
#pragma unroll
    for (int j = 0; j < 8; j++){ s += x[j]; s2 += x[j] * x[j]; }
#pragma unroll
    for (int o = 1; o < 64; o <<= 1){ s += __shfl_xor(s, o); s2 += __shfl_xor(s2, o); }
    float mean = s * (1.f / 512.f);
    float rstd = rsqrtf(s2 * (1.f / 512.f) - mean * mean + 1e-5f);
    int c = l * 8;
    f32x4 y0, y1; bf16x8 ob;
#pragma unroll
    for (int j = 0; j < 4; j++){
        float y = (x[j] - mean) * rstd * g[c + j] + be[c + j];
        y0[j] = y; ob[j] = f2bf(y);
    }
#pragma unroll
    for (int j = 0; j < 4; j++){
        float y = (x[4 + j] - mean) * rstd * g[c + 4 + j] + be[c + 4 + j];
        y1[j] = y; ob[4 + j] = f2bf(y);
    }
    *(f32x4*)(outf + base) = y0;
    *(f32x4*)(outf + base + 4) = y1;
    if (outb) *(bf16x8*)(outb + base) = ob;
}

// ---------------- flash attention (no-max softmax) ----------------
template<int DH, int KN, bool CAT>
__global__ __launch_bounds__(256, 2) void attn_kernel(
    const short* __restrict__ Q1, const short* __restrict__ Q2,
    const short* __restrict__ K1, const short* __restrict__ K2,
    const short* __restrict__ Vt,
    const float* __restrict__ mbias, float* __restrict__ out, float scale2)
{
    constexpr int KT = 64, DV = 64, Qn = 1024, H = 8;
    constexpr int NF = DH / 32;
    constexpr int BPR = DH / 8;
    constexpr int KITER = KT * BPR / 256;
    constexpr int NT = KN / KT;
    __shared__ __attribute__((aligned(16))) short lK[2][KT * DH];
    __shared__ __attribute__((aligned(16))) short lV[2][DV * KT];
    int t = threadIdx.x, w = t >> 6, l = t & 63;
    int cl = l & 15, g = l >> 4;
    int bid = blockIdx.x;
    int bh = (bid & 7) * 8 + (bid >> 6);
    int qb = (bid >> 3) & 7;
    int b = bh >> 3, h = bh & 7;
    int q0 = qb * 128 + w * 32;

    bf16x8 qf[2][NF];
#pragma unroll
    for (int qq = 0; qq < 2; qq++)
#pragma unroll
        for (int f = 0; f < NF; f++){
            if constexpr (CAT){
                const short* src = (f < NF / 2) ? Q1 : Q2;
                qf[qq][f] = *(const bf16x8*)(src + ((long)b * Qn + q0 + qq * 16 + cl) * 512 + h * 64
                                             + (f & (NF / 2 - 1)) * 32 + 8 * g);
            } else {
                qf[qq][f] = *(const bf16x8*)(Q1 + ((long)bh * Qn + q0 + qq * 16 + cl) * DH + f * 32 + 8 * g);
            }
        }

    const short* kp[KITER];
    long kstep[KITER];
#pragma unroll
    for (int i = 0; i < KITER; i++){
        int s_ = i * 256 + t;
        int srow_ = s_ / BPR, blk = s_ % BPR;
        int s32 = srow_ & 31;
        int key = (srow_ & 32) + 8 * ((s32 >> 2) & 3) + 4 * (s32 >> 4) + (s32 & 3);
        int sb = blk ^ (srow_ & 7);
        if constexpr (CAT){
            if (sb < 8){ kp[i] = K1 + ((long)b * KN + key) * 512 + h * 64 + sb * 8; kstep[i] = (long)KT * 512; }
            else       { kp[i] = K2 + ((long)b * KN + key) * 512 + h * 64 + (sb - 8) * 8; kstep[i] = (long)KT * 512; }
        } else {
            kp[i] = K1 + ((long)bh * KN + key) * DH + sb * 8; kstep[i] = (long)KT * DH;
        }
    }
    const short* vp[2];
#pragma unroll
    for (int i = 0; i < 2; i++){
        int s_ = i * 256 + t;
        int srow_ = s_ >> 3, blk = s_ & 7;
        int sb = blk ^ (srow_ & 7);
        vp[i] = Vt + ((long)bh * DV + srow_) * KN + sb * 8;
    }

    auto stage = [&](int d){
#pragma unroll
        for (int i = 0; i < KITER; i++){
            gload_lds16(kp[i], (char*)(&lK[d][0]) + i * 4096 + w * 1024);
            kp[i] += kstep[i];
        }
#pragma unroll
        for (int i = 0; i < 2; i++){
            gload_lds16(vp[i], (char*)(&lV[d][0]) + i * 4096 + w * 1024);
            vp[i] += KT;
        }
    };

    f32x4 st[2][4];
    auto do_qk = [&](int d){
        prio_hi();
#pragma unroll
        for (int o = 0; o < 4; o++){
            int srow_ = o * 16 + cl;
            bf16x8 kf[NF];
#pragma unroll
            for (int f = 0; f < NF; f++){
                int sb = (4 * f + g) ^ (srow_ & 7);
                kf[f] = *(const bf16x8*)(&lK[d][0] + srow_ * DH + sb * 8);
            }
#pragma unroll
            for (int qq = 0; qq < 2; qq++){
                f32x4 acc = f32x4{0.f, 0.f, 0.f, 0.f};
#pragma unroll
                for (int f = 0; f < NF; f++)
                    acc = __builtin_amdgcn_mfma_f32_16x16x32_bf16(kf[f], qf[qq][f], acc, 0, 0, 0);
                st[qq][o] = acc;
            }
        }
        prio_lo();
    };

    const float* mrow = mbias + (long)b * KN;
    bf16x8 vones;
    {
        u32x4 ou; ou[0] = ou[1] = ou[2] = ou[3] = 0x3F803F80u;
        vones = __builtin_bit_cast(bf16x8, ou);
    }
    f32x4 lacc[2];
    f32x4 oacc[2][4];
#pragma unroll
    for (int qq = 0; qq < 2; qq++){
        lacc[qq] = f32x4{0.f, 0.f, 0.f, 0.f};
#pragma unroll
        for (int d = 0; d < 4; d++) oacc[qq][d] = f32x4{0.f, 0.f, 0.f, 0.f};
    }

    f32x4 mb[4];
#pragma unroll
    for (int o = 0; o < 4; o++)
        mb[o] = *(const f32x4*)(mrow + (o >> 1) * 32 + 8 * g + 4 * (o & 1));

    stage(0);
    __syncthreads();
    do_qk(0);

    for (int tt = 0; tt < NT; tt++){
        int cur = tt & 1;
        if (tt + 1 < NT) stage(cur ^ 1);

        bf16x8 pa[2][2];
#pragma unroll
        for (int qq = 0; qq < 2; qq++){
#pragma unroll
            for (int kb = 0; kb < 2; kb++){
                float pA[4], pB[4];
#pragma unroll
                for (int rr = 0; rr < 4; rr++){
                    pA[rr] = exp2fast(fmaf(st[qq][2 * kb][rr], scale2, mb[2 * kb][rr]));
                    pB[rr] = exp2fast(fmaf(st[qq][2 * kb + 1][rr], scale2, mb[2 * kb + 1][rr]));
                }
                u32x4 pk;
                pk[0] = packbf(pA[0], pA[1]);
                pk[1] = packbf(pA[2], pA[3]);
                pk[2] = packbf(pB[0], pB[1]);
                pk[3] = packbf(pB[2], pB[3]);
                pa[qq][kb] = __builtin_bit_cast(bf16x8, pk);
            }
        }
        if (tt + 1 < NT){
#pragma unroll
            for (int o = 0; o < 4; o++)
                mb[o] = *(const f32x4*)(mrow + (tt + 1) * KT + (o >> 1) * 32 + 8 * g + 4 * (o & 1));
        }
        prio_hi();
#pragma unroll
        for (int qq = 0; qq < 2; qq++){
            lacc[qq] = __builtin_amdgcn_mfma_f32_16x16x32_bf16(pa[qq][0], vones, lacc[qq], 0, 0, 0);
            lacc[qq] = __builtin_amdgcn_mfma_f32_16x16x32_bf16(pa[qq][1], vones, lacc[qq], 0, 0, 0);
        }
#pragma unroll
        for (int dvc = 0; dvc < 4; dvc++){
            int vrow = dvc * 16 + cl;
            bf16x8 vf[2];
#pragma unroll
            for (int kb = 0; kb < 2; kb++){
                int sb = (4 * kb + g) ^ (vrow & 7);
                vf[kb] = *(const bf16x8*)(&lV[cur][0] + vrow * KT + sb * 8);
            }
#pragma unroll
            for (int qq = 0; qq < 2; qq++){
                f32x4 o = oacc[qq][dvc];
                o = __builtin_amdgcn_mfma_f32_16x16x32_bf16(pa[qq][0], vf[0], o, 0, 0, 0);
                o = __builtin_amdgcn_mfma_f32_16x16x32_bf16(pa[qq][1], vf[1], o, 0, 0, 0);
                oacc[qq][dvc] = o;
            }
        }
        prio_lo();
        __syncthreads();
        if (tt + 1 < NT) do_qk(cur ^ 1);
    }

#pragma unroll
    for (int qq = 0; qq < 2; qq++){
        float linv[4];
#pragma unroll
        for (int rr = 0; rr < 4; rr++) linv[rr] = 1.f / lacc[qq][rr];
#pragma unroll
        for (int dvc = 0; dvc < 4; dvc++)
#pragma unroll
            for (int rr = 0; rr < 4; rr++){
                int q = q0 + qq * 16 + 4 * g + rr;
                out[(((long)b * Qn + q) * H + h) * DV + dvc * 16 + cl] = oacc[qq][dvc][rr] * linv[rr];
            }
    }
}

// ================= host orchestration =================
extern "C" void kernel_launch(void* const* d_in, const int* in_sizes, int n_in,
                              void* d_out, int out_size, void* d_ws, size_t ws_size,
                              hipStream_t stream)
{
    (void)in_sizes; (void)n_in; (void)out_size; (void)ws_size;
    const int Qn = 1024, Kn = 2048;
    const long MQ = 8L * Qn;   // 8192
    const long MK = 8L * Kn;   // 16384

    const float* queries = (const float*)d_in[0];
    const unsigned char* qmask = (const unsigned char*)d_in[1];
    const float* box  = (const float*)d_in[2];
    const float* ctr  = (const float*)d_in[3];
    const float* kvd  = (const float*)d_in[4];
    const unsigned char* kmask = (const unsigned char*)d_in[5];
    const float* kvp  = (const float*)d_in[6];
    const float* w_qkv = (const float*)d_in[7];  const float* b_qkv = (const float*)d_in[8];
    const float* w_pos = (const float*)d_in[9];  const float* b_pos = (const float*)d_in[10];
    const float* g_sa  = (const float*)d_in[11]; const float* be_sa = (const float*)d_in[12];
    const float* w_caq = (const float*)d_in[13]; const float* b_caq = (const float*)d_in[14];
    const float* w_cakv = (const float*)d_in[15]; const float* b_cakv = (const float*)d_in[16];
    const float* w_caqp = (const float*)d_in[17]; const float* b_caqp = (const float*)d_in[18];
    const float* w_cakp = (const float*)d_in[19]; const float* b_cakp = (const float*)d_in[20];
    const float* g_ca  = (const float*)d_in[21]; const float* be_ca = (const float*)d_in[22];
    const float* w_f1  = (const float*)d_in[23]; const float* b_f1 = (const float*)d_in[24];
    const float* w_f2  = (const float*)d_in[25]; const float* b_f2 = (const float*)d_in[26];
    const float* g_f   = (const float*)d_in[27]; const float* be_f = (const float*)d_in[28];

    char* ws = (char*)d_ws;
    size_t off = 0;
    auto alloc = [&](size_t bytes) -> char* {
        char* p = ws + off;
        off += (bytes + 255) & ~(size_t)255;
        return p;
    };
    short* wTm_qk  = (short*)alloc(1024L * 1536 * 2);
    short* wTv     = (short*)alloc(512L * 512 * 2);
    short* wT_caq  = (short*)alloc(512L * 512 * 2);
    short* wT_cakv = (short*)alloc(1024L * 256 * 2);
    short* wT_caqp = (short*)alloc(512L * 512 * 2);
    short* wT_cakp = (short*)alloc(512L * 256 * 2);
    short* wT_f1   = (short*)alloc(2048L * 512 * 2);
    short* wT_f2   = (short*)alloc(512L * 2048 * 2);
    float* bcomb   = (float*)alloc(1024L * 4);
    short* ctr_bf  = (short*)alloc(MQ * 512 * 2);
    short* kvd_bf  = (short*)alloc(MK * 256 * 2);
    short* kvp_bf  = (short*)alloc(MK * 256 * 2);
    short* saln_bf = (short*)alloc(MQ * 512 * 2);
    short* caln_bf = (short*)alloc(MQ * 512 * 2);
    float* sa_ln_f = (float*)alloc(MQ * 512 * 4);
    float* ca_ln_f = (float*)alloc(MQ * 512 * 4);
    float* att_f   = (float*)alloc(MQ * 512 * 4);
    float* f_out   = (float*)alloc(MQ * 512 * 4);
    short* VtSA    = (short*)alloc(64L * 64 * 1024 * 2);
    short* VtCA    = (short*)alloc(64L * 64 * 2048 * 2);
    float* mb_sa   = (float*)alloc(MQ * 4);
    float* mb_ca   = (float*)alloc(MK * 4);
    short* caK     = (short*)alloc(MK * 512 * 2);   // dedicated (written concurrently with Xcat reads)
    short* cakp_bf = (short*)alloc(MK * 512 * 2);
    short* caq_bf  = (short*)alloc(MQ * 512 * 2);
    short* caqp_bf = (short*)alloc(MQ * 512 * 2);
    char* zone1 = alloc(MQ * 1536 * 2);             // Xcat
    char* zone2 = alloc(MQ * 2048 * 2);             // QKVa | mid_bf

    auto mkgd = [&](const short* A, long lda, const short* Bt, const float* bias,
                    short* Cbf, float* Cf, int M, int N, int K, int flags,
                    short* Vt, int vtColBase, int snShift, int vtSN, int blkStart) -> GD {
        GD d;
        d.A = A; d.Bt = Bt; d.bias = bias; d.Cbf = Cbf; d.Cf = Cf; d.Vt = Vt;
        d.lda = lda; d.N = N; d.K = K; d.flags = flags;
        d.vtColBase = vtColBase; d.snShift = snShift; d.vtSN = vtSN;
        d.blkStart = blkStart; d.nbx = N / 64; d.nblk = (N / 64) * (M / 128);
        return d;
    };
    auto launch_multi = [&](GD6& dd){
        int total = 0;
        for (int i = 0; i < dd.n; i++) total += dd.g[i].nblk;
        for (int i = dd.n; i < 6; i++){ dd.g[i] = dd.g[0]; dd.g[i].blkStart = 0x7fffffff; }
        gemm_multi<<<dim3(total), dim3(128), 0, stream>>>(dd);
    };

    // P0: fused prep + weights
    short* Xcat = (short*)zone1;
    prep_weights<<<dim3(14756), dim3(256), 0, stream>>>(
        queries, box, ctr, kvd, kvp, qmask, kmask, b_qkv, b_pos,
        Xcat, ctr_bf, kvd_bf, kvp_bf, mb_sa, mb_ca, bcomb,
        w_qkv, w_pos, w_caq, w_cakv, w_caqp, w_cakp, w_f1, w_f2,
        wTm_qk, wTv, wT_caq, wT_cakv, wT_caqp, wT_cakp, wT_f1, wT_f2);

    // P1: everything that depends only on prep, in ONE launch (5120 blocks):
    //     qk merged (headsplit), SA V (-> VtSA transposed), cakv (-> caK + VtCA),
    //     cakp, caqp.
    short* QKVa = (short*)zone2;
    short* Qa  = QKVa;
    short* Ka  = QKVa + 64L * 1024 * 64;
    {
        GD6 dd; dd.n = 5;
        int s0 = 0;
        dd.g[0] = mkgd(Xcat, 1536, wTm_qk, bcomb, QKVa, nullptr, (int)MQ, 1024, 1536, 2,
                       nullptr, 0, 0, 0, s0);                       s0 += dd.g[0].nblk;   // 1024
        dd.g[1] = mkgd(kvd_bf, 256, wT_cakv, b_cakv, caK, nullptr, (int)MK, 1024, 256, 4,
                       VtCA, 512, 11, 2048, s0);                    s0 += dd.g[1].nblk;   // 2048
        dd.g[2] = mkgd(kvp_bf, 256, wT_cakp, b_cakp, cakp_bf, nullptr, (int)MK, 512, 256, 0,
                       nullptr, 0, 0, 0, s0);                       s0 += dd.g[2].nblk;   // 1024
        dd.g[3] = mkgd(Xcat, 1536, wTv, b_qkv + 1024, nullptr, nullptr, (int)MQ, 512, 512, 4,
                       VtSA, 0, 10, 1024, s0);                      s0 += dd.g[3].nblk;   // 512
        dd.g[4] = mkgd(ctr_bf, 512, wT_caqp, b_caqp, caqp_bf, nullptr, (int)MQ, 512, 512, 0,
                       nullptr, 0, 0, 0, s0);
        launch_multi(dd);
    }

    // P2: SA attention
    attn_kernel<64, 1024, false><<<dim3(512), dim3(256), 0, stream>>>(
        Qa, nullptr, Ka, nullptr, VtSA, mb_sa, att_f, 0.125f * 1.44269504f);

    // P3: LN1
    ln_fuse<<<dim3((unsigned)(MQ / 4)), dim3(256), 0, stream>>>(queries, att_f, g_sa, be_sa, sa_ln_f, saln_bf);

    // P4: caq (depends on LN1)
    {
        GD6 dd; dd.n = 1;
        dd.g[0] = mkgd(saln_bf, 512, wT_caq, b_caq, caq_bf, nullptr, (int)MQ, 512, 512, 0,
                       nullptr, 0, 0, 0, 0);
        launch_multi(dd);
    }

    // P5: CA attention
    attn_kernel<128, 2048, true><<<dim3(512), dim3(256), 0, stream>>>(
        caq_bf, caqp_bf, caK, cakp_bf, VtCA, mb_ca, att_f, 0.08838834764831845f * 1.44269504f);

    // P6: LN2
    ln_fuse<<<dim3((unsigned)(MQ / 4)), dim3(256), 0, stream>>>(sa_ln_f, att_f, g_ca, be_ca, ca_ln_f, caln_bf);

    // P7: FFN1
    short* mid_bf = (short*)zone2;
    {
        GD6 dd; dd.n = 1;
        dd.g[0] = mkgd(caln_bf, 512, wT_f1, b_f1, mid_bf, nullptr, (int)MQ, 2048, 512, 1,
                       nullptr, 0, 0, 0, 0);
        launch_multi(dd);
    }
    // P8: FFN2
    {
        GD6 dd; dd.n = 1;
        dd.g[0] = mkgd(mid_bf, 2048, wT_f2, b_f2, nullptr, f_out, (int)MQ, 512, 2048, 0,
                       nullptr, 0, 0, 0, 0);
        launch_multi(dd);
    }

    // P9: final LN -> d_out
    ln_fuse<<<dim3((unsigned)(MQ / 4)), dim3(256), 0, stream>>>(ca_ln_f, f_out, g_f, be_f, (float*)d_out, (short*)nullptr);
}

// Round 15
// 299.266 us; speedup vs baseline: 1.0678x; 1.0678x over previous
//
#include <hip/hip_runtime.h>

typedef __attribute__((ext_vector_type(4))) float f32x4;
typedef __attribute__((ext_vector_type(8))) short bf16x8;
typedef __attribute__((ext_vector_type(4))) unsigned int u32x4;

static __device__ __forceinline__ short f2bf(float f){
    unsigned int u = __builtin_bit_cast(unsigned int, f);
    unsigned int r = (u + 0x7fffu + ((u >> 16) & 1u)) >> 16;
    return (short)r;
}
static __device__ __forceinline__ void gload_lds16(const void* g, void* l){
    __builtin_amdgcn_global_load_lds((const __attribute__((address_space(1))) void*)g,
                                     (__attribute__((address_space(3))) void*)l, 16, 0, 0);
}
static __device__ __forceinline__ float exp2fast(float x){
    float r; asm("v_exp_f32 %0, %1" : "=v"(r) : "v"(x)); return r;
}
static __device__ __forceinline__ unsigned int packbf(float lo, float hi){
#if __has_builtin(__builtin_amdgcn_perm)
    return __builtin_amdgcn_perm(__builtin_bit_cast(unsigned int, hi),
                                 __builtin_bit_cast(unsigned int, lo), 0x07060302u);
#else
    return (__builtin_bit_cast(unsigned int, hi) & 0xffff0000u) |
           (__builtin_bit_cast(unsigned int, lo) >> 16);
#endif
}
static __device__ __forceinline__ void prio_hi(){
#if defined(__HIP_DEVICE_COMPILE__)
    __builtin_amdgcn_s_setprio(1);
#endif
}
static __device__ __forceinline__ void prio_lo(){
#if defined(__HIP_DEVICE_COMPILE__)
    __builtin_amdgcn_s_setprio(0);
#endif
}

// ---------------- fused prep: casts + mask bias + bias combine + weight transposes ----------------
static __device__ __forceinline__ void transcast_body(const float* __restrict__ w,
                                                      short* __restrict__ wT,
                                                      int K, int N, int bx, int by, int t){
    int n = bx * 256 + t;
    int k0 = by * 8;
    bf16x8 o;
#pragma unroll
    for (int j = 0; j < 8; j++) o[j] = f2bf(w[(long)(k0 + j) * N + n]);
    *(bf16x8*)(wT + (long)n * K + k0) = o;
}
// TOTAL blocks = 12288 + 32 + 64 + 4 + 2368 = 14756.
__global__ __launch_bounds__(256) void prep_weights(
    const float* __restrict__ queries, const float* __restrict__ box,
    const float* __restrict__ ctr, const float* __restrict__ kvd, const float* __restrict__ kvp,
    const unsigned char* __restrict__ qmask, const unsigned char* __restrict__ kmask,
    const float* __restrict__ b_qkv, const float* __restrict__ b_pos,
    short* __restrict__ Xcat, short* __restrict__ ctr_bf,
    short* __restrict__ kvd_bf, short* __restrict__ kvp_bf,
    float* __restrict__ mb_sa, float* __restrict__ mb_ca, float* __restrict__ bcomb,
    const float* __restrict__ w_qkv, const float* __restrict__ w_pos,
    const float* __restrict__ w_caq, const float* __restrict__ w_cakv,
    const float* __restrict__ w_caqp, const float* __restrict__ w_cakp,
    const float* __restrict__ w_f1, const float* __restrict__ w_f2,
    short* __restrict__ wTm_qk, short* __restrict__ wTv,
    short* __restrict__ wT_caq, short* __restrict__ wT_cakv,
    short* __restrict__ wT_caqp, short* __restrict__ wT_cakp,
    short* __restrict__ wT_f1, short* __restrict__ wT_f2)
{
    int bb = blockIdx.x, t = threadIdx.x;
    if (bb < 12288){
        const float* src; short* dst; long i; long stride; int logRow; int colOff;
        if (bb < 2048){ src = queries; dst = Xcat; i = ((long)bb * 256 + t) * 8; logRow = 9;  stride = 1536; colOff = 0; }
        else if (bb < 6144){ src = box; dst = Xcat; i = ((long)(bb - 2048) * 256 + t) * 8; logRow = 10; stride = 1536; colOff = 512; }
        else if (bb < 8192){ src = ctr; dst = ctr_bf; i = ((long)(bb - 6144) * 256 + t) * 8; logRow = 0; stride = 0; colOff = 0; }
        else if (bb < 10240){ src = kvd; dst = kvd_bf; i = ((long)(bb - 8192) * 256 + t) * 8; logRow = 0; stride = 0; colOff = 0; }
        else { src = kvp; dst = kvp_bf; i = ((long)(bb - 10240) * 256 + t) * 8; logRow = 0; stride = 0; colOff = 0; }
        f32x4 a = *(const f32x4*)(src + i);
        f32x4 b = *(const f32x4*)(src + i + 4);
        bf16x8 o;
#pragma unroll
        for (int j = 0; j < 4; j++){ o[j] = f2bf(a[j]); o[4 + j] = f2bf(b[j]); }
        long oi = logRow ? ((i >> logRow) * stride + colOff + (i & ((1L << logRow) - 1))) : i;
        *(bf16x8*)(dst + oi) = o;
        return;
    }
    if (bb < 12320){ int i = (bb - 12288) * 256 + t; mb_sa[i] = qmask[i] ? -1e30f : 0.f; return; }
    if (bb < 12384){ int i = (bb - 12320) * 256 + t; mb_ca[i] = kmask[i] ? -1e30f : 0.f; return; }
    if (bb < 12388){ int i = (bb - 12384) * 256 + t; if (i < 1024) bcomb[i] = b_qkv[i] + b_pos[i]; return; }
    int wb = bb - 12388;
    if (wb < 768){
        int by = wb / 4, bx = wb % 4;
        int n = bx * 256 + t;
        int k0 = by * 8;
        bf16x8 o;
#pragma unroll
        for (int j = 0; j < 8; j++){
            int kk = k0 + j;
            float v = (kk < 512) ? w_qkv[(long)kk * 1536 + n] : w_pos[(long)(kk - 512) * 1024 + n];
            o[j] = f2bf(v);
        }
        *(bf16x8*)(wTm_qk + (long)n * 1536 + k0) = o;
    }
    else if (wb < 896){
        int lb = wb - 768;
        int by = lb / 2, bx = lb % 2;
        int n = bx * 256 + t;
        int k0 = by * 8;
        bf16x8 o;
#pragma unroll
        for (int j = 0; j < 8; j++) o[j] = f2bf(w_qkv[(long)(k0 + j) * 1536 + 1024 + n]);
        *(bf16x8*)(wTv + (long)n * 512 + k0) = o;
    }
    else if (wb < 1024){ int lb = wb - 896;  transcast_body(w_caq,  wT_caq,  512, 512,  lb % 2, lb / 2, t); }
    else if (wb < 1152){ int lb = wb - 1024; transcast_body(w_cakv, wT_cakv, 256, 1024, lb % 4, lb / 4, t); }
    else if (wb < 1280){ int lb = wb - 1152; transcast_body(w_caqp, wT_caqp, 512, 512,  lb % 2, lb / 2, t); }
    else if (wb < 1344){ int lb = wb - 1280; transcast_body(w_cakp, wT_cakp, 256, 512,  lb % 2, lb / 2, t); }
    else if (wb < 1856){ int lb = wb - 1344; transcast_body(w_f1,   wT_f1,   512, 2048, lb % 8, lb / 8, t); }
    else               { int lb = wb - 1856; transcast_body(w_f2,   wT_f2,   2048, 512, lb % 2, lb / 2, t); }
}

// ---------------- multi-segment GEMM (m97 structure: 4 waves, 128x128, dbuf) ----------------
// 256 threads, 2x2 waves of 64x64 each; BN=128; double-buffered gload_lds staging with
// __syncthreads (compiler-scheduled; 12 waves/CU TLP hides latency — m114). Up to 6
// independent GEMMs per launch; per-segment XCD swizzle. flags: 1=relu; 2=headsplit;
// 4=Vt-transpose for cols>=vtColBase (cols<vtColBase row-major, stride vtColBase).
struct GD {
    const short* A; const short* Bt; const float* bias;
    short* Cbf; float* Cf; short* Vt;
    long lda;
    int N, K, flags, vtColBase, snShift, vtSN, blkStart, nbx, nblk;
};
struct GD6 { GD g[6]; int n; };

__global__ __launch_bounds__(256, 3) void gemm_multi(GD6 dd)
{
    constexpr int BN = 128, BLOCK = 256;
    constexpr int BUF = (128 + BN) * 32;      // shorts per buffer (16KB)
    constexpr int EST = BN + 4;
    __shared__ __attribute__((aligned(16))) char smem[2 * BUF * 2];
    float* lC = (float*)smem;
    int bb = blockIdx.x;
    int si = 0;
#pragma unroll
    for (int i = 1; i < 6; i++) if (i < dd.n && bb >= dd.g[i].blkStart) si = i;
    const short* A = dd.g[si].A;
    const short* Bt = dd.g[si].Bt;
    const float* bias = dd.g[si].bias;
    short* Cbf = dd.g[si].Cbf;
    float* Cf = dd.g[si].Cf;
    short* Vt = dd.g[si].Vt;
    long lda = dd.g[si].lda;
    int N = dd.g[si].N, K = dd.g[si].K, flags = dd.g[si].flags;
    int vtColBase = dd.g[si].vtColBase, snShift = dd.g[si].snShift, vtSN = dd.g[si].vtSN;
    int nbx = dd.g[si].nbx, nblk = dd.g[si].nblk;

    int t = threadIdx.x, w = t >> 6, l = t & 63;
    int cl = l & 15, g = l >> 4;
    int flat = bb - dd.g[si].blkStart;
    int q8 = nblk >> 3;
    int swz = (flat & 7) * q8 + (flat >> 3);
    long r0 = (long)(swz / nbx) * 128, c0 = (long)(swz % nbx) * BN;
    int wr = w >> 1, wc = w & 1;
    f32x4 acc[4][4];
#pragma unroll
    for (int mi = 0; mi < 4; mi++)
#pragma unroll
        for (int ni = 0; ni < 4; ni++) acc[mi][ni] = f32x4{0.f, 0.f, 0.f, 0.f};

    auto stage = [&](int d, int k0){
        char* lA = smem + (size_t)d * BUF * 2;
        char* lB = lA + 128 * 32 * 2;
#pragma unroll
        for (int i = 0; i < 2; i++){
            int s = i * BLOCK + t;
            int row = s >> 2, blk = s & 3;
            int sb = blk ^ (row & 3);
            gload_lds16(A + (r0 + row) * lda + k0 + sb * 8, lA + i * 4096 + w * 1024);
        }
#pragma unroll
        for (int i = 0; i < 2; i++){
            int s = i * BLOCK + t;
            int row = s >> 2, blk = s & 3;
            int sb = blk ^ (row & 3);
            gload_lds16(Bt + (c0 + row) * (long)K + k0 + sb * 8, lB + i * 4096 + w * 1024);
        }
    };

    stage(0, 0);
    __syncthreads();
    int NK = K / 32;
    for (int kt = 0; kt < NK; kt++){
        int cur = kt & 1;
        if (kt + 1 < NK) stage(cur ^ 1, (kt + 1) * 32);
        const short* lA = (const short*)(smem + (size_t)cur * BUF * 2);
        const short* lB = lA + 128 * 32;
        bf16x8 af[4], bfr[4];
#pragma unroll
        for (int mi = 0; mi < 4; mi++){
            int row = wr * 64 + mi * 16 + cl;
            af[mi] = *(const bf16x8*)(lA + row * 32 + (g ^ (row & 3)) * 8);
        }
#pragma unroll
        for (int ni = 0; ni < 4; ni++){
            int row = wc * 64 + ni * 16 + cl;
            bfr[ni] = *(const bf16x8*)(lB + row * 32 + (g ^ (row & 3)) * 8);
        }
        prio_hi();
#pragma unroll
        for (int mi = 0; mi < 4; mi++)
#pragma unroll
            for (int ni = 0; ni < 4; ni++)
                acc[mi][ni] = __builtin_amdgcn_mfma_f32_16x16x32_bf16(af[mi], bfr[ni], acc[mi][ni], 0, 0, 0);
        prio_lo();
        __syncthreads();
    }

    bool vtBlock = (flags & 4) && (c0 >= vtColBase);
#pragma unroll
    for (int mi = 0; mi < 4; mi++){
        __syncthreads();
#pragma unroll
        for (int ni = 0; ni < 4; ni++)
#pragma unroll
            for (int rr = 0; rr < 4; rr++)
                lC[(wr * 16 + g * 4 + rr) * EST + wc * 64 + ni * 16 + cl] = acc[mi][ni][rr];
        __syncthreads();
        if (vtBlock){
            // transposed: write Vt[(b*8+h)*64+dv][kn] coalesced along kn
#pragma unroll
            for (int c2 = 0; c2 < 2; c2++){
                int task = t + BLOCK * c2;
                int col = task & (BN - 1);
                int wrg = (task >> 7) & 1;
                int ch = task >> 8;
                float bv = bias[c0 + col];
                long qg0 = r0 + wrg * 64 + mi * 16 + ch * 8;
                bf16x8 ob;
#pragma unroll
                for (int j = 0; j < 8; j++)
                    ob[j] = f2bf(lC[(wrg * 16 + ch * 8 + j) * EST + col] + bv);
                long dvg = c0 - vtColBase + col;
                long h = dvg >> 6, dvv = dvg & 63;
                long b = qg0 >> snShift;
                long loc = qg0 & ((1L << snShift) - 1);
                *(bf16x8*)(Vt + ((b * 8 + h) * 64 + dvv) * (long)vtSN + loc) = ob;
            }
        } else {
            constexpr int CPR = BN / 8;
#pragma unroll
            for (int c2 = 0; c2 < 32 * CPR / BLOCK; c2++){
                int chunk = t + BLOCK * c2;
                int row = chunk / CPR;
                int coloff = (chunk % CPR) * 8;
                long grow = r0 + (row >> 4) * 64 + mi * 16 + (row & 15);
                long gcol = c0 + coloff;
                f32x4 bv0 = *(const f32x4*)(bias + gcol);
                f32x4 bv1 = *(const f32x4*)(bias + gcol + 4);
                float v[8];
#pragma unroll
                for (int j = 0; j < 8; j++){
                    float x = lC[row * EST + coloff + j] + (j < 4 ? bv0[j] : bv1[j - 4]);
                    if (flags & 1) x = fmaxf(x, 0.f);
                    v[j] = x;
                }
                if (Cf){
                    *(f32x4*)(Cf + grow * N + gcol) = f32x4{v[0], v[1], v[2], v[3]};
                    *(f32x4*)(Cf + grow * N + gcol + 4) = f32x4{v[4], v[5], v[6], v[7]};
                } else {
                    bf16x8 ob;
#pragma unroll
                    for (int j = 0; j < 8; j++) ob[j] = f2bf(v[j]);
                    long idx;
                    if (flags & 2){
                        long part = gcol >> 9;
                        long cc = gcol & 511;
                        long b = grow >> 10, qn = grow & 1023;
                        long h = cc >> 6, d = cc & 63;
                        idx = ((part * 64 + b * 8 + h) * 1024 + qn) * 64 + d;
                    } else if (flags & 4){
                        idx = grow * (long)vtColBase + gcol;
                    } else {
                        idx = grow * N + gcol;
                    }
                    *(bf16x8*)(Cbf + idx) = ob;
                }
            }
        }
    }
}

// ---------------- fused residual + LayerNorm (512 cols), wave-per-row ----------------
__global__ __launch_bounds__(256) void ln_fuse(const float* __restrict__ a, const float* __restrict__ b,
                                               const float* __restrict__ g, const float* __restrict__ be,
                                               float* __restrict__ outf, short* __restrict__ outb){
    int w = threadIdx.x >> 6, l = threadIdx.x & 63;
    long row = (long)blockIdx.x * 4 + w;
    long base = row * 512 + l * 8;
    f32x4 a0 = *(const f32x4*)(a + base);
    f32x4 a1 = *(const f32x4*)(a + base + 4);
    f32x4 b0 = *(const f32x4*)(b + base);
    f32x4 b1 = *(const f32x4*)(b + base + 4);
    float x[8]; float s = 0.f, s2 = 0.f;
#pragma unroll
    for (int j = 0; j < 4; j++){ x[j] = a0[j] + b0[j]; x[4 + j] = a1[j] + b1[j]; }
#pragma unroll
    for (int j = 0; j < 8; j++){ s += x[j]; s2 += x[j] * x[j]; }
#pragma unroll
    for (int o = 1; o < 64; o <<= 1){ s += __shfl_xor(s, o); s2 += __shfl_xor(s2, o); }
    float mean = s * (1.f / 512.f);
    float rstd = rsqrtf(s2 * (1.f / 512.f) - mean * mean + 1e-5f);
    int c = l * 8;
    f32x4 y0, y1; bf16x8 ob;
#pragma unroll
    for (int j = 0; j < 4; j++){
        float y = (x[j] - mean) * rstd * g[c + j] + be[c + j];
        y0[j] = y; ob[j] = f2bf(y);
    }
#pragma unroll
    for (int j = 0; j < 4; j++){
        float y = (x[4 + j] - mean) * rstd * g[c + 4 + j] + be[c + 4 + j];
        y1[j] = y; ob[4 + j] = f2bf(y);
    }
    *(f32x4*)(outf + base) = y0;
    *(f32x4*)(outf + base + 4) = y1;
    if (outb) *(bf16x8*)(outb + base) = ob;
}

// ---------------- flash attention (no-max softmax) ----------------
template<int DH, int KN, bool CAT>
__global__ __launch_bounds__(256, 2) void attn_kernel(
    const short* __restrict__ Q1, const short* __restrict__ Q2,
    const short* __restrict__ K1, const short* __restrict__ K2,
    const short* __restrict__ Vt,
    const float* __restrict__ mbias, float* __restrict__ out, float scale2)
{
    constexpr int KT = 64, DV = 64, Qn = 1024, H = 8;
    constexpr int NF = DH / 32;
    constexpr int BPR = DH / 8;
    constexpr int KITER = KT * BPR / 256;
    constexpr int NT = KN / KT;
    __shared__ __attribute__((aligned(16))) short lK[2][KT * DH];
    __shared__ __attribute__((aligned(16))) short lV[2][DV * KT];
    int t = threadIdx.x, w = t >> 6, l = t & 63;
    int cl = l & 15, g = l >> 4;
    int bid = blockIdx.x;
    int bh = (bid & 7) * 8 + (bid >> 6);
    int qb = (bid >> 3) & 7;
    int b = bh >> 3, h = bh & 7;
    int q0 = qb * 128 + w * 32;

    bf16x8 qf[2][NF];
#pragma unroll
    for (int qq = 0; qq < 2; qq++)
#pragma unroll
        for (int f = 0; f < NF; f++){
            if constexpr (CAT){
                const short* src = (f < NF / 2) ? Q1 : Q2;
                qf[qq][f] = *(const bf16x8*)(src + ((long)b * Qn + q0 + qq * 16 + cl) * 512 + h * 64
                                             + (f & (NF / 2 - 1)) * 32 + 8 * g);
            } else {
                qf[qq][f] = *(const bf16x8*)(Q1 + ((long)bh * Qn + q0 + qq * 16 + cl) * DH + f * 32 + 8 * g);
            }
        }

    const short* kp[KITER];
    long kstep[KITER];
#pragma unroll
    for (int i = 0; i < KITER; i++){
        int s_ = i * 256 + t;
        int srow_ = s_ / BPR, blk = s_ % BPR;
        int s32 = srow_ & 31;
        int key = (srow_ & 32) + 8 * ((s32 >> 2) & 3) + 4 * (s32 >> 4) + (s32 & 3);
        int sb = blk ^ (srow_ & 7);
        if constexpr (CAT){
            if (sb < 8){ kp[i] = K1 + ((long)b * KN + key) * 512 + h * 64 + sb * 8; kstep[i] = (long)KT * 512; }
            else       { kp[i] = K2 + ((long)b * KN + key) * 512 + h * 64 + (sb - 8) * 8; kstep[i] = (long)KT * 512; }
        } else {
            kp[i] = K1 + ((long)bh * KN + key) * DH + sb * 8; kstep[i] = (long)KT * DH;
        }
    }
    const short* vp[2];
#pragma unroll
    for (int i = 0; i < 2; i++){
        int s_ = i * 256 + t;
        int srow_ = s_ >> 3, blk = s_ & 7;
        int sb = blk ^ (srow_ & 7);
        vp[i] = Vt + ((long)bh * DV + srow_) * KN + sb * 8;
    }

    auto stage = [&](int d){
#pragma unroll
        for (int i = 0; i < KITER; i++){
            gload_lds16(kp[i], (char*)(&lK[d][0]) + i * 4096 + w * 1024);
            kp[i] += kstep[i];
        }
#pragma unroll
        for (int i = 0; i < 2; i++){
            gload_lds16(vp[i], (char*)(&lV[d][0]) + i * 4096 + w * 1024);
            vp[i] += KT;
        }
    };

    f32x4 st[2][4];
    auto do_qk = [&](int d){
        prio_hi();
#pragma unroll
        for (int o = 0; o < 4; o++){
            int srow_ = o * 16 + cl;
            bf16x8 kf[NF];
#pragma unroll
            for (int f = 0; f < NF; f++){
                int sb = (4 * f + g) ^ (srow_ & 7);
                kf[f] = *(const bf16x8*)(&lK[d][0] + srow_ * DH + sb * 8);
            }
#pragma unroll
            for (int qq = 0; qq < 2; qq++){
                f32x4 acc = f32x4{0.f, 0.f, 0.f, 0.f};
#pragma unroll
                for (int f = 0; f < NF; f++)
                    acc = __builtin_amdgcn_mfma_f32_16x16x32_bf16(kf[f], qf[qq][f], acc, 0, 0, 0);
                st[qq][o] = acc;
            }
        }
        prio_lo();
    };

    const float* mrow = mbias + (long)b * KN;
    bf16x8 vones;
    {
        u32x4 ou; ou[0] = ou[1] = ou[2] = ou[3] = 0x3F803F80u;
        vones = __builtin_bit_cast(bf16x8, ou);
    }
    f32x4 lacc[2];
    f32x4 oacc[2][4];
#pragma unroll
    for (int qq = 0; qq < 2; qq++){
        lacc[qq] = f32x4{0.f, 0.f, 0.f, 0.f};
#pragma unroll
        for (int d = 0; d < 4; d++) oacc[qq][d] = f32x4{0.f, 0.f, 0.f, 0.f};
    }

    f32x4 mb[4];
#pragma unroll
    for (int o = 0; o < 4; o++)
        mb[o] = *(const f32x4*)(mrow + (o >> 1) * 32 + 8 * g + 4 * (o & 1));

    stage(0);
    __syncthreads();
    do_qk(0);

    for (int tt = 0; tt < NT; tt++){
        int cur = tt & 1;
        if (tt + 1 < NT) stage(cur ^ 1);

        bf16x8 pa[2][2];
#pragma unroll
        for (int qq = 0; qq < 2; qq++){
#pragma unroll
            for (int kb = 0; kb < 2; kb++){
                float pA[4], pB[4];
#pragma unroll
                for (int rr = 0; rr < 4; rr++){
                    pA[rr] = exp2fast(fmaf(st[qq][2 * kb][rr], scale2, mb[2 * kb][rr]));
                    pB[rr] = exp2fast(fmaf(st[qq][2 * kb + 1][rr], scale2, mb[2 * kb + 1][rr]));
                }
                u32x4 pk;
                pk[0] = packbf(pA[0], pA[1]);
                pk[1] = packbf(pA[2], pA[3]);
                pk[2] = packbf(pB[0], pB[1]);
                pk[3] = packbf(pB[2], pB[3]);
                pa[qq][kb] = __builtin_bit_cast(bf16x8, pk);
            }
        }
        if (tt + 1 < NT){
#pragma unroll
            for (int o = 0; o < 4; o++)
                mb[o] = *(const f32x4*)(mrow + (tt + 1) * KT + (o >> 1) * 32 + 8 * g + 4 * (o & 1));
        }
        prio_hi();
#pragma unroll
        for (int qq = 0; qq < 2; qq++){
            lacc[qq] = __builtin_amdgcn_mfma_f32_16x16x32_bf16(pa[qq][0], vones, lacc[qq], 0, 0, 0);
            lacc[qq] = __builtin_amdgcn_mfma_f32_16x16x32_bf16(pa[qq][1], vones, lacc[qq], 0, 0, 0);
        }
#pragma unroll
        for (int dvc = 0; dvc < 4; dvc++){
            int vrow = dvc * 16 + cl;
            bf16x8 vf[2];
#pragma unroll
            for (int kb = 0; kb < 2; kb++){
                int sb = (4 * kb + g) ^ (vrow & 7);
                vf[kb] = *(const bf16x8*)(&lV[cur][0] + vrow * KT + sb * 8);
            }
#pragma unroll
            for (int qq = 0; qq < 2; qq++){
                f32x4 o = oacc[qq][dvc];
                o = __builtin_amdgcn_mfma_f32_16x16x32_bf16(pa[qq][0], vf[0], o, 0, 0, 0);
                o = __builtin_amdgcn_mfma_f32_16x16x32_bf16(pa[qq][1], vf[1], o, 0, 0, 0);
                oacc[qq][dvc] = o;
            }
        }
        prio_lo();
        __syncthreads();
        if (tt + 1 < NT) do_qk(cur ^ 1);
    }

#pragma unroll
    for (int qq = 0; qq < 2; qq++){
        float linv[4];
#pragma unroll
        for (int rr = 0; rr < 4; rr++) linv[rr] = 1.f / lacc[qq][rr];
#pragma unroll
        for (int dvc = 0; dvc < 4; dvc++)
#pragma unroll
            for (int rr = 0; rr < 4; rr++){
                int q = q0 + qq * 16 + 4 * g + rr;
                out[(((long)b * Qn + q) * H + h) * DV + dvc * 16 + cl] = oacc[qq][dvc][rr] * linv[rr];
            }
    }
}

// ================= host orchestration =================
extern "C" void kernel_launch(void* const* d_in, const int* in_sizes, int n_in,
                              void* d_out, int out_size, void* d_ws, size_t ws_size,
                              hipStream_t stream)
{
    (void)in_sizes; (void)n_in; (void)out_size; (void)ws_size;
    const int Qn = 1024, Kn = 2048;
    const long MQ = 8L * Qn;   // 8192
    const long MK = 8L * Kn;   // 16384

    const float* queries = (const float*)d_in[0];
    const unsigned char* qmask = (const unsigned char*)d_in[1];
    const float* box  = (const float*)d_in[2];
    const float* ctr  = (const float*)d_in[3];
    const float* kvd  = (const float*)d_in[4];
    const unsigned char* kmask = (const unsigned char*)d_in[5];
    const float* kvp  = (const float*)d_in[6];
    const float* w_qkv = (const float*)d_in[7];  const float* b_qkv = (const float*)d_in[8];
    const float* w_pos = (const float*)d_in[9];  const float* b_pos = (const float*)d_in[10];
    const float* g_sa  = (const float*)d_in[11]; const float* be_sa = (const float*)d_in[12];
    const float* w_caq = (const float*)d_in[13]; const float* b_caq = (const float*)d_in[14];
    const float* w_cakv = (const float*)d_in[15]; const float* b_cakv = (const float*)d_in[16];
    const float* w_caqp = (const float*)d_in[17]; const float* b_caqp = (const float*)d_in[18];
    const float* w_cakp = (const float*)d_in[19]; const float* b_cakp = (const float*)d_in[20];
    const float* g_ca  = (const float*)d_in[21]; const float* be_ca = (const float*)d_in[22];
    const float* w_f1  = (const float*)d_in[23]; const float* b_f1 = (const float*)d_in[24];
    const float* w_f2  = (const float*)d_in[25]; const float* b_f2 = (const float*)d_in[26];
    const float* g_f   = (const float*)d_in[27]; const float* be_f = (const float*)d_in[28];

    char* ws = (char*)d_ws;
    size_t off = 0;
    auto alloc = [&](size_t bytes) -> char* {
        char* p = ws + off;
        off += (bytes + 255) & ~(size_t)255;
        return p;
    };
    short* wTm_qk  = (short*)alloc(1024L * 1536 * 2);
    short* wTv     = (short*)alloc(512L * 512 * 2);
    short* wT_caq  = (short*)alloc(512L * 512 * 2);
    short* wT_cakv = (short*)alloc(1024L * 256 * 2);
    short* wT_caqp = (short*)alloc(512L * 512 * 2);
    short* wT_cakp = (short*)alloc(512L * 256 * 2);
    short* wT_f1   = (short*)alloc(2048L * 512 * 2);
    short* wT_f2   = (short*)alloc(512L * 2048 * 2);
    float* bcomb   = (float*)alloc(1024L * 4);
    short* ctr_bf  = (short*)alloc(MQ * 512 * 2);
    short* kvd_bf  = (short*)alloc(MK * 256 * 2);
    short* kvp_bf  = (short*)alloc(MK * 256 * 2);
    short* saln_bf = (short*)alloc(MQ * 512 * 2);
    short* caln_bf = (short*)alloc(MQ * 512 * 2);
    float* sa_ln_f = (float*)alloc(MQ * 512 * 4);
    float* ca_ln_f = (float*)alloc(MQ * 512 * 4);
    float* att_f   = (float*)alloc(MQ * 512 * 4);
    float* f_out   = (float*)alloc(MQ * 512 * 4);
    short* VtSA    = (short*)alloc(64L * 64 * 1024 * 2);
    short* VtCA    = (short*)alloc(64L * 64 * 2048 * 2);
    float* mb_sa   = (float*)alloc(MQ * 4);
    float* mb_ca   = (float*)alloc(MK * 4);
    short* caK     = (short*)alloc(MK * 512 * 2);   // dedicated (written while Xcat still live)
    short* cakp_bf = (short*)alloc(MK * 512 * 2);
    short* caq_bf  = (short*)alloc(MQ * 512 * 2);
    short* caqp_bf = (short*)alloc(MQ * 512 * 2);
    char* zone1 = alloc(MQ * 1536 * 2);             // Xcat
    char* zone2 = alloc(MQ * 2048 * 2);             // QKVa | mid_bf

    auto mkgd = [&](const short* A, long lda, const short* Bt, const float* bias,
                    short* Cbf, float* Cf, int M, int N, int K, int flags,
                    short* Vt, int vtColBase, int snShift, int vtSN, int blkStart) -> GD {
        GD d;
        d.A = A; d.Bt = Bt; d.bias = bias; d.Cbf = Cbf; d.Cf = Cf; d.Vt = Vt;
        d.lda = lda; d.N = N; d.K = K; d.flags = flags;
        d.vtColBase = vtColBase; d.snShift = snShift; d.vtSN = vtSN;
        d.blkStart = blkStart; d.nbx = N / 128; d.nblk = (N / 128) * (M / 128);
        return d;
    };
    auto launch_multi = [&](GD6& dd){
        int total = 0;
        for (int i = 0; i < dd.n; i++) total += dd.g[i].nblk;
        for (int i = dd.n; i < 6; i++){ dd.g[i] = dd.g[0]; dd.g[i].blkStart = 0x7fffffff; }
        gemm_multi<<<dim3(total), dim3(256), 0, stream>>>(dd);
    };

    // P0: fused prep + weights
    short* Xcat = (short*)zone1;
    prep_weights<<<dim3(14756), dim3(256), 0, stream>>>(
        queries, box, ctr, kvd, kvp, qmask, kmask, b_qkv, b_pos,
        Xcat, ctr_bf, kvd_bf, kvp_bf, mb_sa, mb_ca, bcomb,
        w_qkv, w_pos, w_caq, w_cakv, w_caqp, w_cakp, w_f1, w_f2,
        wTm_qk, wTv, wT_caq, wT_cakv, wT_caqp, wT_cakp, wT_f1, wT_f2);

    // P1: all prep-dependent GEMMs in ONE launch (2560 blocks, 4-wave):
    //     qk merged (headsplit), cakv (-> caK + VtCA), cakp, SA V (-> VtSA), caqp.
    short* QKVa = (short*)zone2;
    short* Qa  = QKVa;
    short* Ka  = QKVa + 64L * 1024 * 64;
    {
        GD6 dd; dd.n = 5;
        int s0 = 0;
        dd.g[0] = mkgd(Xcat, 1536, wTm_qk, bcomb, QKVa, nullptr, (int)MQ, 1024, 1536, 2,
                       nullptr, 0, 0, 0, s0);                       s0 += dd.g[0].nblk;   // 512
        dd.g[1] = mkgd(kvd_bf, 256, wT_cakv, b_cakv, caK, nullptr, (int)MK, 1024, 256, 4,
                       VtCA, 512, 11, 2048, s0);                    s0 += dd.g[1].nblk;   // 1024
        dd.g[2] = mkgd(kvp_bf, 256, wT_cakp, b_cakp, cakp_bf, nullptr, (int)MK, 512, 256, 0,
                       nullptr, 0, 0, 0, s0);                       s0 += dd.g[2].nblk;   // 512
        dd.g[3] = mkgd(Xcat, 1536, wTv, b_qkv + 1024, nullptr, nullptr, (int)MQ, 512, 512, 4,
                       VtSA, 0, 10, 1024, s0);                      s0 += dd.g[3].nblk;   // 256
        dd.g[4] = mkgd(ctr_bf, 512, wT_caqp, b_caqp, caqp_bf, nullptr, (int)MQ, 512, 512, 0,
                       nullptr, 0, 0, 0, s0);
        launch_multi(dd);
    }

    // P2: SA attention
    attn_kernel<64, 1024, false><<<dim3(512), dim3(256), 0, stream>>>(
        Qa, nullptr, Ka, nullptr, VtSA, mb_sa, att_f, 0.125f * 1.44269504f);

    // P3: LN1
    ln_fuse<<<dim3((unsigned)(MQ / 4)), dim3(256), 0, stream>>>(queries, att_f, g_sa, be_sa, sa_ln_f, saln_bf);

    // P4: caq (depends on LN1)
    {
        GD6 dd; dd.n = 1;
        dd.g[0] = mkgd(saln_bf, 512, wT_caq, b_caq, caq_bf, nullptr, (int)MQ, 512, 512, 0,
                       nullptr, 0, 0, 0, 0);
        launch_multi(dd);
    }

    // P5: CA attention
    attn_kernel<128, 2048, true><<<dim3(512), dim3(256), 0, stream>>>(
        caq_bf, caqp_bf, caK, cakp_bf, VtCA, mb_ca, att_f, 0.08838834764831845f * 1.44269504f);

    // P6: LN2
    ln_fuse<<<dim3((unsigned)(MQ / 4)), dim3(256), 0, stream>>>(sa_ln_f, att_f, g_ca, be_ca, ca_ln_f, caln_bf);

    // P7: FFN1
    short* mid_bf = (short*)zone2;
    {
        GD6 dd; dd.n = 1;
        dd.g[0] = mkgd(caln_bf, 512, wT_f1, b_f1, mid_bf, nullptr, (int)MQ, 2048, 512, 1,
                       nullptr, 0, 0, 0, 0);
        launch_multi(dd);
    }
    // P8: FFN2
    {
        GD6 dd; dd.n = 1;
        dd.g[0] = mkgd(mid_bf, 2048, wT_f2, b_f2, nullptr, f_out, (int)MQ, 512, 2048, 0,
                       nullptr, 0, 0, 0, 0);
        launch_multi(dd);
    }

    // P9: final LN -> d_out
    ln_fuse<<<dim3((unsigned)(MQ / 4)), dim3(256), 0, stream>>>(ca_ln_f, f_out, g_f, be_f, (float*)d_out, (short*)nullptr);
}

// Round 16
// 293.953 us; speedup vs baseline: 1.0871x; 1.0181x over previous
//
#include <hip/hip_runtime.h>

typedef __attribute__((ext_vector_type(4))) float f32x4;
typedef __attribute__((ext_vector_type(8))) short bf16x8;
typedef __attribute__((ext_vector_type(4))) unsigned int u32x4;

static __device__ __forceinline__ float bf2f(short s){
    unsigned int u = ((unsigned int)(unsigned short)s) << 16;
    return __builtin_bit_cast(float, u);
}
static __device__ __forceinline__ short f2bf(float f){
    unsigned int u = __builtin_bit_cast(unsigned int, f);
    unsigned int r = (u + 0x7fffu + ((u >> 16) & 1u)) >> 16;
    return (short)r;
}
static __device__ __forceinline__ void gload_lds16(const void* g, void* l){
    __builtin_amdgcn_global_load_lds((const __attribute__((address_space(1))) void*)g,
                                     (__attribute__((address_space(3))) void*)l, 16, 0, 0);
}
static __device__ __forceinline__ float exp2fast(float x){
    float r; asm("v_exp_f32 %0, %1" : "=v"(r) : "v"(x)); return r;
}
static __device__ __forceinline__ unsigned int packbf(float lo, float hi){
#if __has_builtin(__builtin_amdgcn_perm)
    return __builtin_amdgcn_perm(__builtin_bit_cast(unsigned int, hi),
                                 __builtin_bit_cast(unsigned int, lo), 0x07060302u);
#else
    return (__builtin_bit_cast(unsigned int, hi) & 0xffff0000u) |
           (__builtin_bit_cast(unsigned int, lo) >> 16);
#endif
}
static __device__ __forceinline__ void prio_hi(){
#if defined(__HIP_DEVICE_COMPILE__)
    __builtin_amdgcn_s_setprio(1);
#endif
}
static __device__ __forceinline__ void prio_lo(){
#if defined(__HIP_DEVICE_COMPILE__)
    __builtin_amdgcn_s_setprio(0);
#endif
}

// ---------------- fused prep: casts + mask bias + bias combine + weight transposes ----------------
static __device__ __forceinline__ void transcast_body(const float* __restrict__ w,
                                                      short* __restrict__ wT,
                                                      int K, int N, int bx, int by, int t){
    int n = bx * 256 + t;
    int k0 = by * 8;
    bf16x8 o;
#pragma unroll
    for (int j = 0; j < 8; j++) o[j] = f2bf(w[(long)(k0 + j) * N + n]);
    *(bf16x8*)(wT + (long)n * K + k0) = o;
}
// TOTAL blocks = 12288 + 32 + 64 + 4 + 2368 = 14756.
__global__ __launch_bounds__(256) void prep_weights(
    const float* __restrict__ queries, const float* __restrict__ box,
    const float* __restrict__ ctr, const float* __restrict__ kvd, const float* __restrict__ kvp,
    const unsigned char* __restrict__ qmask, const unsigned char* __restrict__ kmask,
    const float* __restrict__ b_qkv, const float* __restrict__ b_pos,
    short* __restrict__ Xcat, short* __restrict__ ctr_bf,
    short* __restrict__ kvd_bf, short* __restrict__ kvp_bf,
    float* __restrict__ mb_sa, float* __restrict__ mb_ca, float* __restrict__ bcomb,
    const float* __restrict__ w_qkv, const float* __restrict__ w_pos,
    const float* __restrict__ w_caq, const float* __restrict__ w_cakv,
    const float* __restrict__ w_caqp, const float* __restrict__ w_cakp,
    const float* __restrict__ w_f1, const float* __restrict__ w_f2,
    short* __restrict__ wTm_qk, short* __restrict__ wTv,
    short* __restrict__ wT_caq, short* __restrict__ wT_cakv,
    short* __restrict__ wT_caqp, short* __restrict__ wT_cakp,
    short* __restrict__ wT_f1, short* __restrict__ wT_f2)
{
    int bb = blockIdx.x, t = threadIdx.x;
    if (bb < 12288){
        const float* src; short* dst; long i; long stride; int logRow; int colOff;
        if (bb < 2048){ src = queries; dst = Xcat; i = ((long)bb * 256 + t) * 8; logRow = 9;  stride = 1536; colOff = 0; }
        else if (bb < 6144){ src = box; dst = Xcat; i = ((long)(bb - 2048) * 256 + t) * 8; logRow = 10; stride = 1536; colOff = 512; }
        else if (bb < 8192){ src = ctr; dst = ctr_bf; i = ((long)(bb - 6144) * 256 + t) * 8; logRow = 0; stride = 0; colOff = 0; }
        else if (bb < 10240){ src = kvd; dst = kvd_bf; i = ((long)(bb - 8192) * 256 + t) * 8; logRow = 0; stride = 0; colOff = 0; }
        else { src = kvp; dst = kvp_bf; i = ((long)(bb - 10240) * 256 + t) * 8; logRow = 0; stride = 0; colOff = 0; }
        f32x4 a = *(const f32x4*)(src + i);
        f32x4 b = *(const f32x4*)(src + i + 4);
        bf16x8 o;
#pragma unroll
        for (int j = 0; j < 4; j++){ o[j] = f2bf(a[j]); o[4 + j] = f2bf(b[j]); }
        long oi = logRow ? ((i >> logRow) * stride + colOff + (i & ((1L << logRow) - 1))) : i;
        *(bf16x8*)(dst + oi) = o;
        return;
    }
    if (bb < 12320){ int i = (bb - 12288) * 256 + t; mb_sa[i] = qmask[i] ? -1e30f : 0.f; return; }
    if (bb < 12384){ int i = (bb - 12320) * 256 + t; mb_ca[i] = kmask[i] ? -1e30f : 0.f; return; }
    if (bb < 12388){ int i = (bb - 12384) * 256 + t; if (i < 1024) bcomb[i] = b_qkv[i] + b_pos[i]; return; }
    int wb = bb - 12388;
    if (wb < 768){
        int by = wb / 4, bx = wb % 4;
        int n = bx * 256 + t;
        int k0 = by * 8;
        bf16x8 o;
#pragma unroll
        for (int j = 0; j < 8; j++){
            int kk = k0 + j;
            float v = (kk < 512) ? w_qkv[(long)kk * 1536 + n] : w_pos[(long)(kk - 512) * 1024 + n];
            o[j] = f2bf(v);
        }
        *(bf16x8*)(wTm_qk + (long)n * 1536 + k0) = o;
    }
    else if (wb < 896){
        int lb = wb - 768;
        int by = lb / 2, bx = lb % 2;
        int n = bx * 256 + t;
        int k0 = by * 8;
        bf16x8 o;
#pragma unroll
        for (int j = 0; j < 8; j++) o[j] = f2bf(w_qkv[(long)(k0 + j) * 1536 + 1024 + n]);
        *(bf16x8*)(wTv + (long)n * 512 + k0) = o;
    }
    else if (wb < 1024){ int lb = wb - 896;  transcast_body(w_caq,  wT_caq,  512, 512,  lb % 2, lb / 2, t); }
    else if (wb < 1152){ int lb = wb - 1024; transcast_body(w_cakv, wT_cakv, 256, 1024, lb % 4, lb / 4, t); }
    else if (wb < 1280){ int lb = wb - 1152; transcast_body(w_caqp, wT_caqp, 512, 512,  lb % 2, lb / 2, t); }
    else if (wb < 1344){ int lb = wb - 1280; transcast_body(w_cakp, wT_cakp, 256, 512,  lb % 2, lb / 2, t); }
    else if (wb < 1856){ int lb = wb - 1344; transcast_body(w_f1,   wT_f1,   512, 2048, lb % 8, lb / 8, t); }
    else               { int lb = wb - 1856; transcast_body(w_f2,   wT_f2,   2048, 512, lb % 2, lb / 2, t); }
}

// ---------------- multi-segment GEMM (m97 structure: 4 waves, 128x128, dbuf) ----------------
// 256 threads, 2x2 waves of 64x64 each; BN=128; double-buffered gload_lds staging with
// __syncthreads (compiler-scheduled; TLP hides latency — m114). Up to 6 independent
// GEMMs per launch; per-segment XCD swizzle. flags: 1=relu; 2=headsplit;
// 4=Vt-transpose for cols>=vtColBase (cols<vtColBase row-major, stride vtColBase).
struct GD {
    const short* A; const short* Bt; const float* bias;
    short* Cbf; float* Cf; short* Vt;
    long lda;
    int N, K, flags, vtColBase, snShift, vtSN, blkStart, nbx, nblk;
};
struct GD6 { GD g[6]; int n; };

__global__ __launch_bounds__(256, 4) void gemm_multi(GD6 dd)
{
    constexpr int BN = 128, BLOCK = 256;
    constexpr int BUF = (128 + BN) * 32;      // shorts per buffer (16KB)
    constexpr int EST = BN + 4;
    __shared__ __attribute__((aligned(16))) char smem[2 * BUF * 2];
    float* lC = (float*)smem;
    int bb = blockIdx.x;
    int si = 0;
#pragma unroll
    for (int i = 1; i < 6; i++) if (i < dd.n && bb >= dd.g[i].blkStart) si = i;
    const short* A = dd.g[si].A;
    const short* Bt = dd.g[si].Bt;
    const float* bias = dd.g[si].bias;
    short* Cbf = dd.g[si].Cbf;
    float* Cf = dd.g[si].Cf;
    short* Vt = dd.g[si].Vt;
    long lda = dd.g[si].lda;
    int N = dd.g[si].N, K = dd.g[si].K, flags = dd.g[si].flags;
    int vtColBase = dd.g[si].vtColBase, snShift = dd.g[si].snShift, vtSN = dd.g[si].vtSN;
    int nbx = dd.g[si].nbx, nblk = dd.g[si].nblk;

    int t = threadIdx.x, w = t >> 6, l = t & 63;
    int cl = l & 15, g = l >> 4;
    int flat = bb - dd.g[si].blkStart;
    int q8 = nblk >> 3;
    int swz = (flat & 7) * q8 + (flat >> 3);
    long r0 = (long)(swz / nbx) * 128, c0 = (long)(swz % nbx) * BN;
    int wr = w >> 1, wc = w & 1;
    f32x4 acc[4][4];
#pragma unroll
    for (int mi = 0; mi < 4; mi++)
#pragma unroll
        for (int ni = 0; ni < 4; ni++) acc[mi][ni] = f32x4{0.f, 0.f, 0.f, 0.f};

    auto stage = [&](int d, int k0){
        char* lA = smem + (size_t)d * BUF * 2;
        char* lB = lA + 128 * 32 * 2;
#pragma unroll
        for (int i = 0; i < 2; i++){
            int s = i * BLOCK + t;
            int row = s >> 2, blk = s & 3;
            int sb = blk ^ (row & 3);
            gload_lds16(A + (r0 + row) * lda + k0 + sb * 8, lA + i * 4096 + w * 1024);
        }
#pragma unroll
        for (int i = 0; i < 2; i++){
            int s = i * BLOCK + t;
            int row = s >> 2, blk = s & 3;
            int sb = blk ^ (row & 3);
            gload_lds16(Bt + (c0 + row) * (long)K + k0 + sb * 8, lB + i * 4096 + w * 1024);
        }
    };

    stage(0, 0);
    __syncthreads();
    int NK = K / 32;
    for (int kt = 0; kt < NK; kt++){
        int cur = kt & 1;
        if (kt + 1 < NK) stage(cur ^ 1, (kt + 1) * 32);
        const short* lA = (const short*)(smem + (size_t)cur * BUF * 2);
        const short* lB = lA + 128 * 32;
        bf16x8 af[4], bfr[4];
#pragma unroll
        for (int mi = 0; mi < 4; mi++){
            int row = wr * 64 + mi * 16 + cl;
            af[mi] = *(const bf16x8*)(lA + row * 32 + (g ^ (row & 3)) * 8);
        }
#pragma unroll
        for (int ni = 0; ni < 4; ni++){
            int row = wc * 64 + ni * 16 + cl;
            bfr[ni] = *(const bf16x8*)(lB + row * 32 + (g ^ (row & 3)) * 8);
        }
        prio_hi();
#pragma unroll
        for (int mi = 0; mi < 4; mi++)
#pragma unroll
            for (int ni = 0; ni < 4; ni++)
                acc[mi][ni] = __builtin_amdgcn_mfma_f32_16x16x32_bf16(af[mi], bfr[ni], acc[mi][ni], 0, 0, 0);
        prio_lo();
        __syncthreads();
    }

    bool vtBlock = (flags & 4) && (c0 >= vtColBase);
#pragma unroll
    for (int mi = 0; mi < 4; mi++){
        __syncthreads();
#pragma unroll
        for (int ni = 0; ni < 4; ni++)
#pragma unroll
            for (int rr = 0; rr < 4; rr++)
                lC[(wr * 16 + g * 4 + rr) * EST + wc * 64 + ni * 16 + cl] = acc[mi][ni][rr];
        __syncthreads();
        if (vtBlock){
#pragma unroll
            for (int c2 = 0; c2 < 2; c2++){
                int task = t + BLOCK * c2;
                int col = task & (BN - 1);
                int wrg = (task >> 7) & 1;
                int ch = task >> 8;
                float bv = bias[c0 + col];
                long qg0 = r0 + wrg * 64 + mi * 16 + ch * 8;
                bf16x8 ob;
#pragma unroll
                for (int j = 0; j < 8; j++)
                    ob[j] = f2bf(lC[(wrg * 16 + ch * 8 + j) * EST + col] + bv);
                long dvg = c0 - vtColBase + col;
                long h = dvg >> 6, dvv = dvg & 63;
                long b = qg0 >> snShift;
                long loc = qg0 & ((1L << snShift) - 1);
                *(bf16x8*)(Vt + ((b * 8 + h) * 64 + dvv) * (long)vtSN + loc) = ob;
            }
        } else {
            constexpr int CPR = BN / 8;
#pragma unroll
            for (int c2 = 0; c2 < 32 * CPR / BLOCK; c2++){
                int chunk = t + BLOCK * c2;
                int row = chunk / CPR;
                int coloff = (chunk % CPR) * 8;
                long grow = r0 + (row >> 4) * 64 + mi * 16 + (row & 15);
                long gcol = c0 + coloff;
                f32x4 bv0 = *(const f32x4*)(bias + gcol);
                f32x4 bv1 = *(const f32x4*)(bias + gcol + 4);
                float v[8];
#pragma unroll
                for (int j = 0; j < 8; j++){
                    float x = lC[row * EST + coloff + j] + (j < 4 ? bv0[j] : bv1[j - 4]);
                    if (flags & 1) x = fmaxf(x, 0.f);
                    v[j] = x;
                }
                if (Cf){
                    *(f32x4*)(Cf + grow * N + gcol) = f32x4{v[0], v[1], v[2], v[3]};
                    *(f32x4*)(Cf + grow * N + gcol + 4) = f32x4{v[4], v[5], v[6], v[7]};
                } else {
                    bf16x8 ob;
#pragma unroll
                    for (int j = 0; j < 8; j++) ob[j] = f2bf(v[j]);
                    long idx;
                    if (flags & 2){
                        long part = gcol >> 9;
                        long cc = gcol & 511;
                        long b = grow >> 10, qn = grow & 1023;
                        long h = cc >> 6, d = cc & 63;
                        idx = ((part * 64 + b * 8 + h) * 1024 + qn) * 64 + d;
                    } else if (flags & 4){
                        idx = grow * (long)vtColBase + gcol;
                    } else {
                        idx = grow * N + gcol;
                    }
                    *(bf16x8*)(Cbf + idx) = ob;
                }
            }
        }
    }
}

// ---------------- fused residual + LayerNorm (512 cols), wave-per-row ----------------
// a: fp32 residual; b: bf16 branch output (attention / FFN) — halves the read.
__global__ __launch_bounds__(256) void ln_fuse(const float* __restrict__ a, const short* __restrict__ b,
                                               const float* __restrict__ g, const float* __restrict__ be,
                                               float* __restrict__ outf, short* __restrict__ outb){
    int w = threadIdx.x >> 6, l = threadIdx.x & 63;
    long row = (long)blockIdx.x * 4 + w;
    long base = row * 512 + l * 8;
    f32x4 a0 = *(const f32x4*)(a + base);
    f32x4 a1 = *(const f32x4*)(a + base + 4);
    bf16x8 bb = *(const bf16x8*)(b + base);
    float x[8]; float s = 0.f, s2 = 0.f;
#pragma unroll
    for (int j = 0; j < 4; j++){ x[j] = a0[j] + bf2f(bb[j]); x[4 + j] = a1[j] + bf2f(bb[4 + j]); }
#pragma unroll
    for (int j = 0; j < 8; j++){ s += x[j]; s2 += x[j] * x[j]; }
#pragma unroll
    for (int o = 1; o < 64; o <<= 1){ s += __shfl_xor(s, o); s2 += __shfl_xor(s2, o); }
    float mean = s * (1.f / 512.f);
    float rstd = rsqrtf(s2 * (1.f / 512.f) - mean * mean + 1e-5f);
    int c = l * 8;
    f32x4 y0, y1; bf16x8 ob;
#pragma unroll
    for (int j = 0; j < 4; j++){
        float y = (x[j] - mean) * rstd * g[c + j] + be[c + j];
        y0[j] = y; ob[j] = f2bf(y);
    }
#pragma unroll
    for (int j = 0; j < 4; j++){
        float y = (x[4 + j] - mean) * rstd * g[c + 4 + j] + be[c + 4 + j];
        y1[j] = y; ob[4 + j] = f2bf(y);
    }
    *(f32x4*)(outf + base) = y0;
    *(f32x4*)(outf + base + 4) = y1;
    if (outb) *(bf16x8*)(outb + base) = ob;
}

// ---------------- flash attention (no-max softmax, bf16 output) ----------------
template<int DH, int KN, bool CAT>
__global__ __launch_bounds__(256, 2) void attn_kernel(
    const short* __restrict__ Q1, const short* __restrict__ Q2,
    const short* __restrict__ K1, const short* __restrict__ K2,
    const short* __restrict__ Vt,
    const float* __restrict__ mbias, short* __restrict__ out, float scale2)
{
    constexpr int KT = 64, DV = 64, Qn = 1024, H = 8;
    constexpr int NF = DH / 32;
    constexpr int BPR = DH / 8;
    constexpr int KITER = KT * BPR / 256;
    constexpr int NT = KN / KT;
    __shared__ __attribute__((aligned(16))) short lK[2][KT * DH];
    __shared__ __attribute__((aligned(16))) short lV[2][DV * KT];
    int t = threadIdx.x, w = t >> 6, l = t & 63;
    int cl = l & 15, g = l >> 4;
    int bid = blockIdx.x;
    int bh = (bid & 7) * 8 + (bid >> 6);
    int qb = (bid >> 3) & 7;
    int b = bh >> 3, h = bh & 7;
    int q0 = qb * 128 + w * 32;

    bf16x8 qf[2][NF];
#pragma unroll
    for (int qq = 0; qq < 2; qq++)
#pragma unroll
        for (int f = 0; f < NF; f++){
            if constexpr (CAT){
                const short* src = (f < NF / 2) ? Q1 : Q2;
                qf[qq][f] = *(const bf16x8*)(src + ((long)b * Qn + q0 + qq * 16 + cl) * 512 + h * 64
                                             + (f & (NF / 2 - 1)) * 32 + 8 * g);
            } else {
                qf[qq][f] = *(const bf16x8*)(Q1 + ((long)bh * Qn + q0 + qq * 16 + cl) * DH + f * 32 + 8 * g);
            }
        }

    const short* kp[KITER];
    long kstep[KITER];
#pragma unroll
    for (int i = 0; i < KITER; i++){
        int s_ = i * 256 + t;
        int srow_ = s_ / BPR, blk = s_ % BPR;
        int s32 = srow_ & 31;
        int key = (srow_ & 32) + 8 * ((s32 >> 2) & 3) + 4 * (s32 >> 4) + (s32 & 3);
        int sb = blk ^ (srow_ & 7);
        if constexpr (CAT){
            if (sb < 8){ kp[i] = K1 + ((long)b * KN + key) * 512 + h * 64 + sb * 8; kstep[i] = (long)KT * 512; }
            else       { kp[i] = K2 + ((long)b * KN + key) * 512 + h * 64 + (sb - 8) * 8; kstep[i] = (long)KT * 512; }
        } else {
            kp[i] = K1 + ((long)bh * KN + key) * DH + sb * 8; kstep[i] = (long)KT * DH;
        }
    }
    const short* vp[2];
#pragma unroll
    for (int i = 0; i < 2; i++){
        int s_ = i * 256 + t;
        int srow_ = s_ >> 3, blk = s_ & 7;
        int sb = blk ^ (srow_ & 7);
        vp[i] = Vt + ((long)bh * DV + srow_) * KN + sb * 8;
    }

    auto stage = [&](int d){
#pragma unroll
        for (int i = 0; i < KITER; i++){
            gload_lds16(kp[i], (char*)(&lK[d][0]) + i * 4096 + w * 1024);
            kp[i] += kstep[i];
        }
#pragma unroll
        for (int i = 0; i < 2; i++){
            gload_lds16(vp[i], (char*)(&lV[d][0]) + i * 4096 + w * 1024);
            vp[i] += KT;
        }
    };

    f32x4 st[2][4];
    auto do_qk = [&](int d){
        prio_hi();
#pragma unroll
        for (int o = 0; o < 4; o++){
            int srow_ = o * 16 + cl;
            bf16x8 kf[NF];
#pragma unroll
            for (int f = 0; f < NF; f++){
                int sb = (4 * f + g) ^ (srow_ & 7);
                kf[f] = *(const bf16x8*)(&lK[d][0] + srow_ * DH + sb * 8);
            }
#pragma unroll
            for (int qq = 0; qq < 2; qq++){
                f32x4 acc = f32x4{0.f, 0.f, 0.f, 0.f};
#pragma unroll
                for (int f = 0; f < NF; f++)
                    acc = __builtin_amdgcn_mfma_f32_16x16x32_bf16(kf[f], qf[qq][f], acc, 0, 0, 0);
                st[qq][o] = acc;
            }
        }
        prio_lo();
    };

    const float* mrow = mbias + (long)b * KN;
    bf16x8 vones;
    {
        u32x4 ou; ou[0] = ou[1] = ou[2] = ou[3] = 0x3F803F80u;
        vones = __builtin_bit_cast(bf16x8, ou);
    }
    f32x4 lacc[2];
    f32x4 oacc[2][4];
#pragma unroll
    for (int qq = 0; qq < 2; qq++){
        lacc[qq] = f32x4{0.f, 0.f, 0.f, 0.f};
#pragma unroll
        for (int d = 0; d < 4; d++) oacc[qq][d] = f32x4{0.f, 0.f, 0.f, 0.f};
    }

    f32x4 mb[4];
#pragma unroll
    for (int o = 0; o < 4; o++)
        mb[o] = *(const f32x4*)(mrow + (o >> 1) * 32 + 8 * g + 4 * (o & 1));

    stage(0);
    __syncthreads();
    do_qk(0);

    for (int tt = 0; tt < NT; tt++){
        int cur = tt & 1;
        if (tt + 1 < NT) stage(cur ^ 1);

        bf16x8 pa[2][2];
#pragma unroll
        for (int qq = 0; qq < 2; qq++){
#pragma unroll
            for (int kb = 0; kb < 2; kb++){
                float pA[4], pB[4];
#pragma unroll
                for (int rr = 0; rr < 4; rr++){
                    pA[rr] = exp2fast(fmaf(st[qq][2 * kb][rr], scale2, mb[2 * kb][rr]));
                    pB[rr] = exp2fast(fmaf(st[qq][2 * kb + 1][rr], scale2, mb[2 * kb + 1][rr]));
                }
                u32x4 pk;
                pk[0] = packbf(pA[0], pA[1]);
                pk[1] = packbf(pA[2], pA[3]);
                pk[2] = packbf(pB[0], pB[1]);
                pk[3] = packbf(pB[2], pB[3]);
                pa[qq][kb] = __builtin_bit_cast(bf16x8, pk);
            }
        }
        if (tt + 1 < NT){
#pragma unroll
            for (int o = 0; o < 4; o++)
                mb[o] = *(const f32x4*)(mrow + (tt + 1) * KT + (o >> 1) * 32 + 8 * g + 4 * (o & 1));
        }
        prio_hi();
#pragma unroll
        for (int qq = 0; qq < 2; qq++){
            lacc[qq] = __builtin_amdgcn_mfma_f32_16x16x32_bf16(pa[qq][0], vones, lacc[qq], 0, 0, 0);
            lacc[qq] = __builtin_amdgcn_mfma_f32_16x16x32_bf16(pa[qq][1], vones, lacc[qq], 0, 0, 0);
        }
#pragma unroll
        for (int dvc = 0; dvc < 4; dvc++){
            int vrow = dvc * 16 + cl;
            bf16x8 vf[2];
#pragma unroll
            for (int kb = 0; kb < 2; kb++){
                int sb = (4 * kb + g) ^ (vrow & 7);
                vf[kb] = *(const bf16x8*)(&lV[cur][0] + vrow * KT + sb * 8);
            }
#pragma unroll
            for (int qq = 0; qq < 2; qq++){
                f32x4 o = oacc[qq][dvc];
                o = __builtin_amdgcn_mfma_f32_16x16x32_bf16(pa[qq][0], vf[0], o, 0, 0, 0);
                o = __builtin_amdgcn_mfma_f32_16x16x32_bf16(pa[qq][1], vf[1], o, 0, 0, 0);
                oacc[qq][dvc] = o;
            }
        }
        prio_lo();
        __syncthreads();
        if (tt + 1 < NT) do_qk(cur ^ 1);
    }

#pragma unroll
    for (int qq = 0; qq < 2; qq++){
        float linv[4];
#pragma unroll
        for (int rr = 0; rr < 4; rr++) linv[rr] = 1.f / lacc[qq][rr];
#pragma unroll
        for (int dvc = 0; dvc < 4; dvc++)
#pragma unroll
            for (int rr = 0; rr < 4; rr++){
                int q = q0 + qq * 16 + 4 * g + rr;
                out[(((long)b * Qn + q) * H + h) * DV + dvc * 16 + cl] = f2bf(oacc[qq][dvc][rr] * linv[rr]);
            }
    }
}

// ================= host orchestration =================
extern "C" void kernel_launch(void* const* d_in, const int* in_sizes, int n_in,
                              void* d_out, int out_size, void* d_ws, size_t ws_size,
                              hipStream_t stream)
{
    (void)in_sizes; (void)n_in; (void)out_size; (void)ws_size;
    const int Qn = 1024, Kn = 2048;
    const long MQ = 8L * Qn;   // 8192
    const long MK = 8L * Kn;   // 16384

    const float* queries = (const float*)d_in[0];
    const unsigned char* qmask = (const unsigned char*)d_in[1];
    const float* box  = (const float*)d_in[2];
    const float* ctr  = (const float*)d_in[3];
    const float* kvd  = (const float*)d_in[4];
    const unsigned char* kmask = (const unsigned char*)d_in[5];
    const float* kvp  = (const float*)d_in[6];
    const float* w_qkv = (const float*)d_in[7];  const float* b_qkv = (const float*)d_in[8];
    const float* w_pos = (const float*)d_in[9];  const float* b_pos = (const float*)d_in[10];
    const float* g_sa  = (const float*)d_in[11]; const float* be_sa = (const float*)d_in[12];
    const float* w_caq = (const float*)d_in[13]; const float* b_caq = (const float*)d_in[14];
    const float* w_cakv = (const float*)d_in[15]; const float* b_cakv = (const float*)d_in[16];
    const float* w_caqp = (const float*)d_in[17]; const float* b_caqp = (const float*)d_in[18];
    const float* w_cakp = (const float*)d_in[19]; const float* b_cakp = (const float*)d_in[20];
    const float* g_ca  = (const float*)d_in[21]; const float* be_ca = (const float*)d_in[22];
    const float* w_f1  = (const float*)d_in[23]; const float* b_f1 = (const float*)d_in[24];
    const float* w_f2  = (const float*)d_in[25]; const float* b_f2 = (const float*)d_in[26];
    const float* g_f   = (const float*)d_in[27]; const float* be_f = (const float*)d_in[28];

    char* ws = (char*)d_ws;
    size_t off = 0;
    auto alloc = [&](size_t bytes) -> char* {
        char* p = ws + off;
        off += (bytes + 255) & ~(size_t)255;
        return p;
    };
    short* wTm_qk  = (short*)alloc(1024L * 1536 * 2);
    short* wTv     = (short*)alloc(512L * 512 * 2);
    short* wT_caq  = (short*)alloc(512L * 512 * 2);
    short* wT_cakv = (short*)alloc(1024L * 256 * 2);
    short* wT_caqp = (short*)alloc(512L * 512 * 2);
    short* wT_cakp = (short*)alloc(512L * 256 * 2);
    short* wT_f1   = (short*)alloc(2048L * 512 * 2);
    short* wT_f2   = (short*)alloc(512L * 2048 * 2);
    float* bcomb   = (float*)alloc(1024L * 4);
    short* ctr_bf  = (short*)alloc(MQ * 512 * 2);
    short* kvd_bf  = (short*)alloc(MK * 256 * 2);
    short* kvp_bf  = (short*)alloc(MK * 256 * 2);
    short* saln_bf = (short*)alloc(MQ * 512 * 2);
    short* caln_bf = (short*)alloc(MQ * 512 * 2);
    float* sa_ln_f = (float*)alloc(MQ * 512 * 4);
    float* ca_ln_f = (float*)alloc(MQ * 512 * 4);
    short* att_bf  = (short*)alloc(MQ * 512 * 2);   // attention out (bf16)
    short* f_out   = (short*)alloc(MQ * 512 * 2);   // FFN out (bf16)
    short* VtSA    = (short*)alloc(64L * 64 * 1024 * 2);
    short* VtCA    = (short*)alloc(64L * 64 * 2048 * 2);
    float* mb_sa   = (float*)alloc(MQ * 4);
    float* mb_ca   = (float*)alloc(MK * 4);
    short* caK     = (short*)alloc(MK * 512 * 2);
    short* cakp_bf = (short*)alloc(MK * 512 * 2);
    short* caq_bf  = (short*)alloc(MQ * 512 * 2);
    short* caqp_bf = (short*)alloc(MQ * 512 * 2);
    char* zone1 = alloc(MQ * 1536 * 2);             // Xcat
    char* zone2 = alloc(MQ * 2048 * 2);             // QKVa | mid_bf

    auto mkgd = [&](const short* A, long lda, const short* Bt, const float* bias,
                    short* Cbf, float* Cf, int M, int N, int K, int flags,
                    short* Vt, int vtColBase, int snShift, int vtSN, int blkStart) -> GD {
        GD d;
        d.A = A; d.Bt = Bt; d.bias = bias; d.Cbf = Cbf; d.Cf = Cf; d.Vt = Vt;
        d.lda = lda; d.N = N; d.K = K; d.flags = flags;
        d.vtColBase = vtColBase; d.snShift = snShift; d.vtSN = vtSN;
        d.blkStart = blkStart; d.nbx = N / 128; d.nblk = (N / 128) * (M / 128);
        return d;
    };
    auto launch_multi = [&](GD6& dd){
        int total = 0;
        for (int i = 0; i < dd.n; i++) total += dd.g[i].nblk;
        for (int i = dd.n; i < 6; i++){ dd.g[i] = dd.g[0]; dd.g[i].blkStart = 0x7fffffff; }
        gemm_multi<<<dim3(total), dim3(256), 0, stream>>>(dd);
    };

    // P0: fused prep + weights
    short* Xcat = (short*)zone1;
    prep_weights<<<dim3(14756), dim3(256), 0, stream>>>(
        queries, box, ctr, kvd, kvp, qmask, kmask, b_qkv, b_pos,
        Xcat, ctr_bf, kvd_bf, kvp_bf, mb_sa, mb_ca, bcomb,
        w_qkv, w_pos, w_caq, w_cakv, w_caqp, w_cakp, w_f1, w_f2,
        wTm_qk, wTv, wT_caq, wT_cakv, wT_caqp, wT_cakp, wT_f1, wT_f2);

    // P1: all prep-dependent GEMMs in ONE launch (2560 blocks, 4-wave)
    short* QKVa = (short*)zone2;
    short* Qa  = QKVa;
    short* Ka  = QKVa + 64L * 1024 * 64;
    {
        GD6 dd; dd.n = 5;
        int s0 = 0;
        dd.g[0] = mkgd(Xcat, 1536, wTm_qk, bcomb, QKVa, nullptr, (int)MQ, 1024, 1536, 2,
                       nullptr, 0, 0, 0, s0);                       s0 += dd.g[0].nblk;
        dd.g[1] = mkgd(kvd_bf, 256, wT_cakv, b_cakv, caK, nullptr, (int)MK, 1024, 256, 4,
                       VtCA, 512, 11, 2048, s0);                    s0 += dd.g[1].nblk;
        dd.g[2] = mkgd(kvp_bf, 256, wT_cakp, b_cakp, cakp_bf, nullptr, (int)MK, 512, 256, 0,
                       nullptr, 0, 0, 0, s0);                       s0 += dd.g[2].nblk;
        dd.g[3] = mkgd(Xcat, 1536, wTv, b_qkv + 1024, nullptr, nullptr, (int)MQ, 512, 512, 4,
                       VtSA, 0, 10, 1024, s0);                      s0 += dd.g[3].nblk;
        dd.g[4] = mkgd(ctr_bf, 512, wT_caqp, b_caqp, caqp_bf, nullptr, (int)MQ, 512, 512, 0,
                       nullptr, 0, 0, 0, s0);
        launch_multi(dd);
    }

    // P2: SA attention (bf16 out)
    attn_kernel<64, 1024, false><<<dim3(512), dim3(256), 0, stream>>>(
        Qa, nullptr, Ka, nullptr, VtSA, mb_sa, att_bf, 0.125f * 1.44269504f);

    // P3: LN1
    ln_fuse<<<dim3((unsigned)(MQ / 4)), dim3(256), 0, stream>>>(queries, att_bf, g_sa, be_sa, sa_ln_f, saln_bf);

    // P4: caq
    {
        GD6 dd; dd.n = 1;
        dd.g[0] = mkgd(saln_bf, 512, wT_caq, b_caq, caq_bf, nullptr, (int)MQ, 512, 512, 0,
                       nullptr, 0, 0, 0, 0);
        launch_multi(dd);
    }

    // P5: CA attention (bf16 out)
    attn_kernel<128, 2048, true><<<dim3(512), dim3(256), 0, stream>>>(
        caq_bf, caqp_bf, caK, cakp_bf, VtCA, mb_ca, att_bf, 0.08838834764831845f * 1.44269504f);

    // P6: LN2
    ln_fuse<<<dim3((unsigned)(MQ / 4)), dim3(256), 0, stream>>>(sa_ln_f, att_bf, g_ca, be_ca, ca_ln_f, caln_bf);

    // P7: FFN1
    short* mid_bf = (short*)zone2;
    {
        GD6 dd; dd.n = 1;
        dd.g[0] = mkgd(caln_bf, 512, wT_f1, b_f1, mid_bf, nullptr, (int)MQ, 2048, 512, 1,
                       nullptr, 0, 0, 0, 0);
        launch_multi(dd);
    }
    // P8: FFN2 (bf16 out)
    {
        GD6 dd; dd.n = 1;
        dd.g[0] = mkgd(mid_bf, 2048, wT_f2, b_f2, f_out, nullptr, (int)MQ, 512, 2048, 0,
                       nullptr, 0, 0, 0, 0);
        launch_multi(dd);
    }

    // P9: final LN -> d_out
    ln_fuse<<<dim3((unsigned)(MQ / 4)), dim3(256), 0, stream>>>(ca_ln_f, f_out, g_f, be_f, (float*)d_out, (short*)nullptr);
}

// Round 17
// 292.526 us; speedup vs baseline: 1.0924x; 1.0049x over previous
//
#include <hip/hip_runtime.h>

typedef __attribute__((ext_vector_type(4))) float f32x4;
typedef __attribute__((ext_vector_type(8))) short bf16x8;
typedef __attribute__((ext_vector_type(4))) unsigned int u32x4;

static __device__ __forceinline__ float bf2f(short s){
    unsigned int u = ((unsigned int)(unsigned short)s) << 16;
    return __builtin_bit_cast(float, u);
}
static __device__ __forceinline__ short f2bf(float f){
    unsigned int u = __builtin_bit_cast(unsigned int, f);
    unsigned int r = (u + 0x7fffu + ((u >> 16) & 1u)) >> 16;
    return (short)r;
}
static __device__ __forceinline__ void gload_lds16(const void* g, void* l){
    __builtin_amdgcn_global_load_lds((const __attribute__((address_space(1))) void*)g,
                                     (__attribute__((address_space(3))) void*)l, 16, 0, 0);
}
static __device__ __forceinline__ float exp2fast(float x){
    float r; asm("v_exp_f32 %0, %1" : "=v"(r) : "v"(x)); return r;
}
static __device__ __forceinline__ unsigned int packbf(float lo, float hi){
#if __has_builtin(__builtin_amdgcn_perm)
    return __builtin_amdgcn_perm(__builtin_bit_cast(unsigned int, hi),
                                 __builtin_bit_cast(unsigned int, lo), 0x07060302u);
#else
    return (__builtin_bit_cast(unsigned int, hi) & 0xffff0000u) |
           (__builtin_bit_cast(unsigned int, lo) >> 16);
#endif
}
static __device__ __forceinline__ void prio_hi(){
#if defined(__HIP_DEVICE_COMPILE__)
    __builtin_amdgcn_s_setprio(1);
#endif
}
static __device__ __forceinline__ void prio_lo(){
#if defined(__HIP_DEVICE_COMPILE__)
    __builtin_amdgcn_s_setprio(0);
#endif
}

// ---------------- fused prep: casts + mask bias + bias combine + weight transposes ----------------
static __device__ __forceinline__ void transcast_body(const float* __restrict__ w,
                                                      short* __restrict__ wT,
                                                      int K, int N, int bx, int by, int t){
    int n = bx * 256 + t;
    int k0 = by * 8;
    bf16x8 o;
#pragma unroll
    for (int j = 0; j < 8; j++) o[j] = f2bf(w[(long)(k0 + j) * N + n]);
    *(bf16x8*)(wT + (long)n * K + k0) = o;
}
// TOTAL blocks = 12288 + 32 + 64 + 4 + 2368 = 14756.
__global__ __launch_bounds__(256) void prep_weights(
    const float* __restrict__ queries, const float* __restrict__ box,
    const float* __restrict__ ctr, const float* __restrict__ kvd, const float* __restrict__ kvp,
    const unsigned char* __restrict__ qmask, const unsigned char* __restrict__ kmask,
    const float* __restrict__ b_qkv, const float* __restrict__ b_pos,
    short* __restrict__ Xcat, short* __restrict__ ctr_bf,
    short* __restrict__ kvd_bf, short* __restrict__ kvp_bf,
    float* __restrict__ mb_sa, float* __restrict__ mb_ca, float* __restrict__ bcomb,
    const float* __restrict__ w_qkv, const float* __restrict__ w_pos,
    const float* __restrict__ w_caq, const float* __restrict__ w_cakv,
    const float* __restrict__ w_caqp, const float* __restrict__ w_cakp,
    const float* __restrict__ w_f1, const float* __restrict__ w_f2,
    short* __restrict__ wTm_qk, short* __restrict__ wTv,
    short* __restrict__ wT_caq, short* __restrict__ wT_cakv,
    short* __restrict__ wT_caqp, short* __restrict__ wT_cakp,
    short* __restrict__ wT_f1, short* __restrict__ wT_f2)
{
    int bb = blockIdx.x, t = threadIdx.x;
    if (bb < 12288){
        const float* src; short* dst; long i; long stride; int logRow; int colOff;
        if (bb < 2048){ src = queries; dst = Xcat; i = ((long)bb * 256 + t) * 8; logRow = 9;  stride = 1536; colOff = 0; }
        else if (bb < 6144){ src = box; dst = Xcat; i = ((long)(bb - 2048) * 256 + t) * 8; logRow = 10; stride = 1536; colOff = 512; }
        else if (bb < 8192){ src = ctr; dst = ctr_bf; i = ((long)(bb - 6144) * 256 + t) * 8; logRow = 0; stride = 0; colOff = 0; }
        else if (bb < 10240){ src = kvd; dst = kvd_bf; i = ((long)(bb - 8192) * 256 + t) * 8; logRow = 0; stride = 0; colOff = 0; }
        else { src = kvp; dst = kvp_bf; i = ((long)(bb - 10240) * 256 + t) * 8; logRow = 0; stride = 0; colOff = 0; }
        f32x4 a = *(const f32x4*)(src + i);
        f32x4 b = *(const f32x4*)(src + i + 4);
        bf16x8 o;
#pragma unroll
        for (int j = 0; j < 4; j++){ o[j] = f2bf(a[j]); o[4 + j] = f2bf(b[j]); }
        long oi = logRow ? ((i >> logRow) * stride + colOff + (i & ((1L << logRow) - 1))) : i;
        *(bf16x8*)(dst + oi) = o;
        return;
    }
    if (bb < 12320){ int i = (bb - 12288) * 256 + t; mb_sa[i] = qmask[i] ? -1e30f : 0.f; return; }
    if (bb < 12384){ int i = (bb - 12320) * 256 + t; mb_ca[i] = kmask[i] ? -1e30f : 0.f; return; }
    if (bb < 12388){ int i = (bb - 12384) * 256 + t; if (i < 1024) bcomb[i] = b_qkv[i] + b_pos[i]; return; }
    int wb = bb - 12388;
    if (wb < 768){
        int by = wb / 4, bx = wb % 4;
        int n = bx * 256 + t;
        int k0 = by * 8;
        bf16x8 o;
#pragma unroll
        for (int j = 0; j < 8; j++){
            int kk = k0 + j;
            float v = (kk < 512) ? w_qkv[(long)kk * 1536 + n] : w_pos[(long)(kk - 512) * 1024 + n];
            o[j] = f2bf(v);
        }
        *(bf16x8*)(wTm_qk + (long)n * 1536 + k0) = o;
    }
    else if (wb < 896){
        int lb = wb - 768;
        int by = lb / 2, bx = lb % 2;
        int n = bx * 256 + t;
        int k0 = by * 8;
        bf16x8 o;
#pragma unroll
        for (int j = 0; j < 8; j++) o[j] = f2bf(w_qkv[(long)(k0 + j) * 1536 + 1024 + n]);
        *(bf16x8*)(wTv + (long)n * 512 + k0) = o;
    }
    else if (wb < 1024){ int lb = wb - 896;  transcast_body(w_caq,  wT_caq,  512, 512,  lb % 2, lb / 2, t); }
    else if (wb < 1152){ int lb = wb - 1024; transcast_body(w_cakv, wT_cakv, 256, 1024, lb % 4, lb / 4, t); }
    else if (wb < 1280){ int lb = wb - 1152; transcast_body(w_caqp, wT_caqp, 512, 512,  lb % 2, lb / 2, t); }
    else if (wb < 1344){ int lb = wb - 1280; transcast_body(w_cakp, wT_cakp, 256, 512,  lb % 2, lb / 2, t); }
    else if (wb < 1856){ int lb = wb - 1344; transcast_body(w_f1,   wT_f1,   512, 2048, lb % 8, lb / 8, t); }
    else               { int lb = wb - 1856; transcast_body(w_f2,   wT_f2,   2048, 512, lb % 2, lb / 2, t); }
}

// ---------------- GEMM body (m97 structure: 4 waves, 128x128, dbuf, 32KB smem) ----------------
struct GD {
    const short* A; const short* Bt; const float* bias;
    short* Cbf; float* Cf; short* Vt;
    long lda;
    int N, K, flags, vtColBase, snShift, vtSN, blkStart, nbx, nblk;
};
struct GD6 { GD g[6]; int n; };

static __device__ void gemm_body(char* smem, const GD6& dd, int bb)
{
    constexpr int BN = 128, BLOCK = 256;
    constexpr int BUF = (128 + BN) * 32;      // shorts per buffer (16KB)
    constexpr int EST = BN + 4;
    float* lC = (float*)smem;
    int si = 0;
#pragma unroll
    for (int i = 1; i < 6; i++) if (i < dd.n && bb >= dd.g[i].blkStart) si = i;
    const short* A = dd.g[si].A;
    const short* Bt = dd.g[si].Bt;
    const float* bias = dd.g[si].bias;
    short* Cbf = dd.g[si].Cbf;
    float* Cf = dd.g[si].Cf;
    short* Vt = dd.g[si].Vt;
    long lda = dd.g[si].lda;
    int N = dd.g[si].N, K = dd.g[si].K, flags = dd.g[si].flags;
    int vtColBase = dd.g[si].vtColBase, snShift = dd.g[si].snShift, vtSN = dd.g[si].vtSN;
    int nbx = dd.g[si].nbx, nblk = dd.g[si].nblk;

    int t = threadIdx.x, w = t >> 6, l = t & 63;
    int cl = l & 15, g = l >> 4;
    int flat = bb - dd.g[si].blkStart;
    int q8 = nblk >> 3;
    int swz = (flat & 7) * q8 + (flat >> 3);
    long r0 = (long)(swz / nbx) * 128, c0 = (long)(swz % nbx) * BN;
    int wr = w >> 1, wc = w & 1;
    f32x4 acc[4][4];
#pragma unroll
    for (int mi = 0; mi < 4; mi++)
#pragma unroll
        for (int ni = 0; ni < 4; ni++) acc[mi][ni] = f32x4{0.f, 0.f, 0.f, 0.f};

    auto stage = [&](int d, int k0){
        char* lA = smem + (size_t)d * BUF * 2;
        char* lB = lA + 128 * 32 * 2;
#pragma unroll
        for (int i = 0; i < 2; i++){
            int s = i * BLOCK + t;
            int row = s >> 2, blk = s & 3;
            int sb = blk ^ (row & 3);
            gload_lds16(A + (r0 + row) * lda + k0 + sb * 8, lA + i * 4096 + w * 1024);
        }
#pragma unroll
        for (int i = 0; i < 2; i++){
            int s = i * BLOCK + t;
            int row = s >> 2, blk = s & 3;
            int sb = blk ^ (row & 3);
            gload_lds16(Bt + (c0 + row) * (long)K + k0 + sb * 8, lB + i * 4096 + w * 1024);
        }
    };

    stage(0, 0);
    __syncthreads();
    int NK = K / 32;
    for (int kt = 0; kt < NK; kt++){
        int cur = kt & 1;
        if (kt + 1 < NK) stage(cur ^ 1, (kt + 1) * 32);
        const short* lA = (const short*)(smem + (size_t)cur * BUF * 2);
        const short* lB = lA + 128 * 32;
        bf16x8 af[4], bfr[4];
#pragma unroll
        for (int mi = 0; mi < 4; mi++){
            int row = wr * 64 + mi * 16 + cl;
            af[mi] = *(const bf16x8*)(lA + row * 32 + (g ^ (row & 3)) * 8);
        }
#pragma unroll
        for (int ni = 0; ni < 4; ni++){
            int row = wc * 64 + ni * 16 + cl;
            bfr[ni] = *(const bf16x8*)(lB + row * 32 + (g ^ (row & 3)) * 8);
        }
        prio_hi();
#pragma unroll
        for (int mi = 0; mi < 4; mi++)
#pragma unroll
            for (int ni = 0; ni < 4; ni++)
                acc[mi][ni] = __builtin_amdgcn_mfma_f32_16x16x32_bf16(af[mi], bfr[ni], acc[mi][ni], 0, 0, 0);
        prio_lo();
        __syncthreads();
    }

    bool vtBlock = (flags & 4) && (c0 >= vtColBase);
#pragma unroll
    for (int mi = 0; mi < 4; mi++){
        __syncthreads();
#pragma unroll
        for (int ni = 0; ni < 4; ni++)
#pragma unroll
            for (int rr = 0; rr < 4; rr++)
                lC[(wr * 16 + g * 4 + rr) * EST + wc * 64 + ni * 16 + cl] = acc[mi][ni][rr];
        __syncthreads();
        if (vtBlock){
#pragma unroll
            for (int c2 = 0; c2 < 2; c2++){
                int task = t + BLOCK * c2;
                int col = task & (BN - 1);
                int wrg = (task >> 7) & 1;
                int ch = task >> 8;
                float bv = bias[c0 + col];
                long qg0 = r0 + wrg * 64 + mi * 16 + ch * 8;
                bf16x8 ob;
#pragma unroll
                for (int j = 0; j < 8; j++)
                    ob[j] = f2bf(lC[(wrg * 16 + ch * 8 + j) * EST + col] + bv);
                long dvg = c0 - vtColBase + col;
                long h = dvg >> 6, dvv = dvg & 63;
                long b = qg0 >> snShift;
                long loc = qg0 & ((1L << snShift) - 1);
                *(bf16x8*)(Vt + ((b * 8 + h) * 64 + dvv) * (long)vtSN + loc) = ob;
            }
        } else {
            constexpr int CPR = BN / 8;
#pragma unroll
            for (int c2 = 0; c2 < 32 * CPR / BLOCK; c2++){
                int chunk = t + BLOCK * c2;
                int row = chunk / CPR;
                int coloff = (chunk % CPR) * 8;
                long grow = r0 + (row >> 4) * 64 + mi * 16 + (row & 15);
                long gcol = c0 + coloff;
                f32x4 bv0 = *(const f32x4*)(bias + gcol);
                f32x4 bv1 = *(const f32x4*)(bias + gcol + 4);
                float v[8];
#pragma unroll
                for (int j = 0; j < 8; j++){
                    float x = lC[row * EST + coloff + j] + (j < 4 ? bv0[j] : bv1[j - 4]);
                    if (flags & 1) x = fmaxf(x, 0.f);
                    v[j] = x;
                }
                if (Cf){
                    *(f32x4*)(Cf + grow * N + gcol) = f32x4{v[0], v[1], v[2], v[3]};
                    *(f32x4*)(Cf + grow * N + gcol + 4) = f32x4{v[4], v[5], v[6], v[7]};
                } else {
                    bf16x8 ob;
#pragma unroll
                    for (int j = 0; j < 8; j++) ob[j] = f2bf(v[j]);
                    long idx;
                    if (flags & 2){
                        long part = gcol >> 9;
                        long cc = gcol & 511;
                        long b = grow >> 10, qn = grow & 1023;
                        long h = cc >> 6, d = cc & 63;
                        idx = ((part * 64 + b * 8 + h) * 1024 + qn) * 64 + d;
                    } else if (flags & 4){
                        idx = grow * (long)vtColBase + gcol;
                    } else {
                        idx = grow * N + gcol;
                    }
                    *(bf16x8*)(Cbf + idx) = ob;
                }
            }
        }
    }
}

__global__ __launch_bounds__(256, 4) void gemm_multi(GD6 dd){
    __shared__ __attribute__((aligned(16))) char smem[32768];
    gemm_body(smem, dd, blockIdx.x);
}

// ---------------- flash attention body (no-max softmax, bf16 output) ----------------
struct AttnArgs {
    const short *Q1, *Q2, *K1, *K2, *Vt;
    const float* mbias; short* out; float scale2;
};

template<int DH, int KN, bool CAT>
static __device__ void attn_body(char* smemraw, const AttnArgs& a, int bid)
{
    constexpr int KT = 64, DV = 64, Qn = 1024, H = 8;
    constexpr int NF = DH / 32;
    constexpr int BPR = DH / 8;
    constexpr int KITER = KT * BPR / 256;
    constexpr int NT = KN / KT;
    short (*lK)[KT * DH] = (short(*)[KT * DH])smemraw;
    short (*lV)[DV * KT] = (short(*)[DV * KT])(smemraw + 2 * KT * DH * 2);
    const short* Q1 = a.Q1; const short* Q2 = a.Q2;
    const short* K1 = a.K1; const short* K2 = a.K2;
    const short* Vt = a.Vt;
    float scale2 = a.scale2;
    int t = threadIdx.x, w = t >> 6, l = t & 63;
    int cl = l & 15, g = l >> 4;
    int bh = (bid & 7) * 8 + (bid >> 6);
    int qb = (bid >> 3) & 7;
    int b = bh >> 3, h = bh & 7;
    int q0 = qb * 128 + w * 32;

    bf16x8 qf[2][NF];
#pragma unroll
    for (int qq = 0; qq < 2; qq++)
#pragma unroll
        for (int f = 0; f < NF; f++){
            if constexpr (CAT){
                const short* src = (f < NF / 2) ? Q1 : Q2;
                qf[qq][f] = *(const bf16x8*)(src + ((long)b * Qn + q0 + qq * 16 + cl) * 512 + h * 64
                                             + (f & (NF / 2 - 1)) * 32 + 8 * g);
            } else {
                qf[qq][f] = *(const bf16x8*)(Q1 + ((long)bh * Qn + q0 + qq * 16 + cl) * DH + f * 32 + 8 * g);
            }
        }

    const short* kp[KITER];
    long kstep[KITER];
#pragma unroll
    for (int i = 0; i < KITER; i++){
        int s_ = i * 256 + t;
        int srow_ = s_ / BPR, blk = s_ % BPR;
        int s32 = srow_ & 31;
        int key = (srow_ & 32) + 8 * ((s32 >> 2) & 3) + 4 * (s32 >> 4) + (s32 & 3);
        int sb = blk ^ (srow_ & 7);
        if constexpr (CAT){
            if (sb < 8){ kp[i] = K1 + ((long)b * KN + key) * 512 + h * 64 + sb * 8; kstep[i] = (long)KT * 512; }
            else       { kp[i] = K2 + ((long)b * KN + key) * 512 + h * 64 + (sb - 8) * 8; kstep[i] = (long)KT * 512; }
        } else {
            kp[i] = K1 + ((long)bh * KN + key) * DH + sb * 8; kstep[i] = (long)KT * DH;
        }
    }
    const short* vp[2];
#pragma unroll
    for (int i = 0; i < 2; i++){
        int s_ = i * 256 + t;
        int srow_ = s_ >> 3, blk = s_ & 7;
        int sb = blk ^ (srow_ & 7);
        vp[i] = Vt + ((long)bh * DV + srow_) * KN + sb * 8;
    }

    auto stage = [&](int d){
#pragma unroll
        for (int i = 0; i < KITER; i++){
            gload_lds16(kp[i], (char*)(&lK[d][0]) + i * 4096 + w * 1024);
            kp[i] += kstep[i];
        }
#pragma unroll
        for (int i = 0; i < 2; i++){
            gload_lds16(vp[i], (char*)(&lV[d][0]) + i * 4096 + w * 1024);
            vp[i] += KT;
        }
    };

    f32x4 st[2][4];
    auto do_qk = [&](int d){
        prio_hi();
#pragma unroll
        for (int o = 0; o < 4; o++){
            int srow_ = o * 16 + cl;
            bf16x8 kf[NF];
#pragma unroll
            for (int f = 0; f < NF; f++){
                int sb = (4 * f + g) ^ (srow_ & 7);
                kf[f] = *(const bf16x8*)(&lK[d][0] + srow_ * DH + sb * 8);
            }
#pragma unroll
            for (int qq = 0; qq < 2; qq++){
                f32x4 acc = f32x4{0.f, 0.f, 0.f, 0.f};
#pragma unroll
                for (int f = 0; f < NF; f++)
                    acc = __builtin_amdgcn_mfma_f32_16x16x32_bf16(kf[f], qf[qq][f], acc, 0, 0, 0);
                st[qq][o] = acc;
            }
        }
        prio_lo();
    };

    const float* mrow = a.mbias + (long)b * KN;
    bf16x8 vones;
    {
        u32x4 ou; ou[0] = ou[1] = ou[2] = ou[3] = 0x3F803F80u;
        vones = __builtin_bit_cast(bf16x8, ou);
    }
    f32x4 lacc[2];
    f32x4 oacc[2][4];
#pragma unroll
    for (int qq = 0; qq < 2; qq++){
        lacc[qq] = f32x4{0.f, 0.f, 0.f, 0.f};
#pragma unroll
        for (int d = 0; d < 4; d++) oacc[qq][d] = f32x4{0.f, 0.f, 0.f, 0.f};
    }

    f32x4 mb[4];
#pragma unroll
    for (int o = 0; o < 4; o++)
        mb[o] = *(const f32x4*)(mrow + (o >> 1) * 32 + 8 * g + 4 * (o & 1));

    stage(0);
    __syncthreads();
    do_qk(0);

    for (int tt = 0; tt < NT; tt++){
        int cur = tt & 1;
        if (tt + 1 < NT) stage(cur ^ 1);

        bf16x8 pa[2][2];
#pragma unroll
        for (int qq = 0; qq < 2; qq++){
#pragma unroll
            for (int kb = 0; kb < 2; kb++){
                float pA[4], pB[4];
#pragma unroll
                for (int rr = 0; rr < 4; rr++){
                    pA[rr] = exp2fast(fmaf(st[qq][2 * kb][rr], scale2, mb[2 * kb][rr]));
                    pB[rr] = exp2fast(fmaf(st[qq][2 * kb + 1][rr], scale2, mb[2 * kb + 1][rr]));
                }
                u32x4 pk;
                pk[0] = packbf(pA[0], pA[1]);
                pk[1] = packbf(pA[2], pA[3]);
                pk[2] = packbf(pB[0], pB[1]);
                pk[3] = packbf(pB[2], pB[3]);
                pa[qq][kb] = __builtin_bit_cast(bf16x8, pk);
            }
        }
        if (tt + 1 < NT){
#pragma unroll
            for (int o = 0; o < 4; o++)
                mb[o] = *(const f32x4*)(mrow + (tt + 1) * KT + (o >> 1) * 32 + 8 * g + 4 * (o & 1));
        }
        prio_hi();
#pragma unroll
        for (int qq = 0; qq < 2; qq++){
            lacc[qq] = __builtin_amdgcn_mfma_f32_16x16x32_bf16(pa[qq][0], vones, lacc[qq], 0, 0, 0);
            lacc[qq] = __builtin_amdgcn_mfma_f32_16x16x32_bf16(pa[qq][1], vones, lacc[qq], 0, 0, 0);
        }
#pragma unroll
        for (int dvc = 0; dvc < 4; dvc++){
            int vrow = dvc * 16 + cl;
            bf16x8 vf[2];
#pragma unroll
            for (int kb = 0; kb < 2; kb++){
                int sb = (4 * kb + g) ^ (vrow & 7);
                vf[kb] = *(const bf16x8*)(&lV[cur][0] + vrow * KT + sb * 8);
            }
#pragma unroll
            for (int qq = 0; qq < 2; qq++){
                f32x4 o = oacc[qq][dvc];
                o = __builtin_amdgcn_mfma_f32_16x16x32_bf16(pa[qq][0], vf[0], o, 0, 0, 0);
                o = __builtin_amdgcn_mfma_f32_16x16x32_bf16(pa[qq][1], vf[1], o, 0, 0, 0);
                oacc[qq][dvc] = o;
            }
        }
        prio_lo();
        __syncthreads();
        if (tt + 1 < NT) do_qk(cur ^ 1);
    }

#pragma unroll
    for (int qq = 0; qq < 2; qq++){
        float linv[4];
#pragma unroll
        for (int rr = 0; rr < 4; rr++) linv[rr] = 1.f / lacc[qq][rr];
#pragma unroll
        for (int dvc = 0; dvc < 4; dvc++)
#pragma unroll
            for (int rr = 0; rr < 4; rr++){
                int q = q0 + qq * 16 + 4 * g + rr;
                a.out[(((long)b * Qn + q) * H + h) * DV + dvc * 16 + cl] = f2bf(oacc[qq][dvc][rr] * linv[rr]);
            }
    }
}

// CA attention standalone (48KB LDS)
__global__ __launch_bounds__(256, 2) void attn_ca(AttnArgs a){
    __shared__ __attribute__((aligned(16))) char smem[2 * 64 * 128 * 2 + 2 * 64 * 64 * 2];
    attn_body<128, 2048, true>(smem, a, blockIdx.x);
}

// SA attention (512 blocks) + independent CA-projection GEMMs co-scheduled (32KB LDS both)
__global__ __launch_bounds__(256, 2) void attn_sa_gemm(AttnArgs a, GD6 dd, int nAttn){
    __shared__ __attribute__((aligned(16))) char smem[32768];
    if ((int)blockIdx.x < nAttn) attn_body<64, 1024, false>(smem, a, blockIdx.x);
    else gemm_body(smem, dd, blockIdx.x - nAttn);
}

// ---------------- fused residual + LayerNorm (512 cols), wave-per-row ----------------
__global__ __launch_bounds__(256) void ln_fuse(const float* __restrict__ a, const short* __restrict__ b,
                                               const float* __restrict__ g, const float* __restrict__ be,
                                               float* __restrict__ outf, short* __restrict__ outb){
    int w = threadIdx.x >> 6, l = threadIdx.x & 63;
    long row = (long)blockIdx.x * 4 + w;
    long base = row * 512 + l * 8;
    f32x4 a0 = *(const f32x4*)(a + base);
    f32x4 a1 = *(const f32x4*)(a + base + 4);
    bf16x8 bb = *(const bf16x8*)(b + base);
    float x[8]; float s = 0.f, s2 = 0.f;
#pragma unroll
    for (int j = 0; j < 4; j++){ x[j] = a0[j] + bf2f(bb[j]); x[4 + j] = a1[j] + bf2f(bb[4 + j]); }
#pragma unroll
    for (int j = 0; j < 8; j++){ s += x[j]; s2 += x[j] * x[j]; }
#pragma unroll
    for (int o = 1; o < 64; o <<= 1){ s += __shfl_xor(s, o); s2 += __shfl_xor(s2, o); }
    float mean = s * (1.f / 512.f);
    float rstd = rsqrtf(s2 * (1.f / 512.f) - mean * mean + 1e-5f);
    int c = l * 8;
    f32x4 y0, y1; bf16x8 ob;
#pragma unroll
    for (int j = 0; j < 4; j++){
        float y = (x[j] - mean) * rstd * g[c + j] + be[c + j];
        y0[j] = y; ob[j] = f2bf(y);
    }
#pragma unroll
    for (int j = 0; j < 4; j++){
        float y = (x[4 + j] - mean) * rstd * g[c + 4 + j] + be[c + 4 + j];
        y1[j] = y; ob[4 + j] = f2bf(y);
    }
    *(f32x4*)(outf + base) = y0;
    *(f32x4*)(outf + base + 4) = y1;
    if (outb) *(bf16x8*)(outb + base) = ob;
}

// ================= host orchestration =================
extern "C" void kernel_launch(void* const* d_in, const int* in_sizes, int n_in,
                              void* d_out, int out_size, void* d_ws, size_t ws_size,
                              hipStream_t stream)
{
    (void)in_sizes; (void)n_in; (void)out_size; (void)ws_size;
    const int Qn = 1024, Kn = 2048;
    const long MQ = 8L * Qn;   // 8192
    const long MK = 8L * Kn;   // 16384

    const float* queries = (const float*)d_in[0];
    const unsigned char* qmask = (const unsigned char*)d_in[1];
    const float* box  = (const float*)d_in[2];
    const float* ctr  = (const float*)d_in[3];
    const float* kvd  = (const float*)d_in[4];
    const unsigned char* kmask = (const unsigned char*)d_in[5];
    const float* kvp  = (const float*)d_in[6];
    const float* w_qkv = (const float*)d_in[7];  const float* b_qkv = (const float*)d_in[8];
    const float* w_pos = (const float*)d_in[9];  const float* b_pos = (const float*)d_in[10];
    const float* g_sa  = (const float*)d_in[11]; const float* be_sa = (const float*)d_in[12];
    const float* w_caq = (const float*)d_in[13]; const float* b_caq = (const float*)d_in[14];
    const float* w_cakv = (const float*)d_in[15]; const float* b_cakv = (const float*)d_in[16];
    const float* w_caqp = (const float*)d_in[17]; const float* b_caqp = (const float*)d_in[18];
    const float* w_cakp = (const float*)d_in[19]; const float* b_cakp = (const float*)d_in[20];
    const float* g_ca  = (const float*)d_in[21]; const float* be_ca = (const float*)d_in[22];
    const float* w_f1  = (const float*)d_in[23]; const float* b_f1 = (const float*)d_in[24];
    const float* w_f2  = (const float*)d_in[25]; const float* b_f2 = (const float*)d_in[26];
    const float* g_f   = (const float*)d_in[27]; const float* be_f = (const float*)d_in[28];

    char* ws = (char*)d_ws;
    size_t off = 0;
    auto alloc = [&](size_t bytes) -> char* {
        char* p = ws + off;
        off += (bytes + 255) & ~(size_t)255;
        return p;
    };
    short* wTm_qk  = (short*)alloc(1024L * 1536 * 2);
    short* wTv     = (short*)alloc(512L * 512 * 2);
    short* wT_caq  = (short*)alloc(512L * 512 * 2);
    short* wT_cakv = (short*)alloc(1024L * 256 * 2);
    short* wT_caqp = (short*)alloc(512L * 512 * 2);
    short* wT_cakp = (short*)alloc(512L * 256 * 2);
    short* wT_f1   = (short*)alloc(2048L * 512 * 2);
    short* wT_f2   = (short*)alloc(512L * 2048 * 2);
    float* bcomb   = (float*)alloc(1024L * 4);
    short* ctr_bf  = (short*)alloc(MQ * 512 * 2);
    short* kvd_bf  = (short*)alloc(MK * 256 * 2);
    short* kvp_bf  = (short*)alloc(MK * 256 * 2);
    short* saln_bf = (short*)alloc(MQ * 512 * 2);
    short* caln_bf = (short*)alloc(MQ * 512 * 2);
    float* sa_ln_f = (float*)alloc(MQ * 512 * 4);
    float* ca_ln_f = (float*)alloc(MQ * 512 * 4);
    short* att_bf  = (short*)alloc(MQ * 512 * 2);
    short* f_out   = (short*)alloc(MQ * 512 * 2);
    short* VtSA    = (short*)alloc(64L * 64 * 1024 * 2);
    short* VtCA    = (short*)alloc(64L * 64 * 2048 * 2);
    float* mb_sa   = (float*)alloc(MQ * 4);
    float* mb_ca   = (float*)alloc(MK * 4);
    short* caK     = (short*)alloc(MK * 512 * 2);
    short* cakp_bf = (short*)alloc(MK * 512 * 2);
    short* caq_bf  = (short*)alloc(MQ * 512 * 2);
    short* caqp_bf = (short*)alloc(MQ * 512 * 2);
    char* zone1 = alloc(MQ * 1536 * 2);             // Xcat
    char* zone2 = alloc(MQ * 2048 * 2);             // QKVa | mid_bf

    auto mkgd = [&](const short* A, long lda, const short* Bt, const float* bias,
                    short* Cbf, float* Cf, int M, int N, int K, int flags,
                    short* Vt, int vtColBase, int snShift, int vtSN, int blkStart) -> GD {
        GD d;
        d.A = A; d.Bt = Bt; d.bias = bias; d.Cbf = Cbf; d.Cf = Cf; d.Vt = Vt;
        d.lda = lda; d.N = N; d.K = K; d.flags = flags;
        d.vtColBase = vtColBase; d.snShift = snShift; d.vtSN = vtSN;
        d.blkStart = blkStart; d.nbx = N / 128; d.nblk = (N / 128) * (M / 128);
        return d;
    };
    auto pad_gd = [&](GD6& dd){
        for (int i = dd.n; i < 6; i++){ dd.g[i] = dd.g[0]; dd.g[i].blkStart = 0x7fffffff; }
    };
    auto launch_multi = [&](GD6& dd){
        int total = 0;
        for (int i = 0; i < dd.n; i++) total += dd.g[i].nblk;
        pad_gd(dd);
        gemm_multi<<<dim3(total), dim3(256), 0, stream>>>(dd);
    };

    // P0: fused prep + weights
    short* Xcat = (short*)zone1;
    prep_weights<<<dim3(14756), dim3(256), 0, stream>>>(
        queries, box, ctr, kvd, kvp, qmask, kmask, b_qkv, b_pos,
        Xcat, ctr_bf, kvd_bf, kvp_bf, mb_sa, mb_ca, bcomb,
        w_qkv, w_pos, w_caq, w_cakv, w_caqp, w_cakp, w_f1, w_f2,
        wTm_qk, wTv, wT_caq, wT_cakv, wT_caqp, wT_cakp, wT_f1, wT_f2);

    // P1: SA-path GEMMs only: qk merged (headsplit) + V (-> VtSA transposed)
    short* QKVa = (short*)zone2;
    short* Qa  = QKVa;
    short* Ka  = QKVa + 64L * 1024 * 64;
    {
        GD6 dd; dd.n = 2;
        dd.g[0] = mkgd(Xcat, 1536, wTm_qk, bcomb, QKVa, nullptr, (int)MQ, 1024, 1536, 2,
                       nullptr, 0, 0, 0, 0);
        dd.g[1] = mkgd(Xcat, 1536, wTv, b_qkv + 1024, nullptr, nullptr, (int)MQ, 512, 512, 4,
                       VtSA, 0, 10, 1024, dd.g[0].nblk);
        launch_multi(dd);
    }

    // P2: SA attention (512 blocks) co-scheduled with CA projections (cakv, cakp, caqp)
    {
        AttnArgs aa;
        aa.Q1 = Qa; aa.Q2 = nullptr; aa.K1 = Ka; aa.K2 = nullptr; aa.Vt = VtSA;
        aa.mbias = mb_sa; aa.out = att_bf; aa.scale2 = 0.125f * 1.44269504f;
        GD6 dd; dd.n = 3;
        int s0 = 0;
        dd.g[0] = mkgd(kvd_bf, 256, wT_cakv, b_cakv, caK, nullptr, (int)MK, 1024, 256, 4,
                       VtCA, 512, 11, 2048, s0);                    s0 += dd.g[0].nblk;   // 1024
        dd.g[1] = mkgd(kvp_bf, 256, wT_cakp, b_cakp, cakp_bf, nullptr, (int)MK, 512, 256, 0,
                       nullptr, 0, 0, 0, s0);                       s0 += dd.g[1].nblk;   // 512
        dd.g[2] = mkgd(ctr_bf, 512, wT_caqp, b_caqp, caqp_bf, nullptr, (int)MQ, 512, 512, 0,
                       nullptr, 0, 0, 0, s0);                       s0 += dd.g[2].nblk;   // 256
        pad_gd(dd);
        attn_sa_gemm<<<dim3(512 + s0), dim3(256), 0, stream>>>(aa, dd, 512);
    }

    // P3: LN1
    ln_fuse<<<dim3((unsigned)(MQ / 4)), dim3(256), 0, stream>>>(queries, att_bf, g_sa, be_sa, sa_ln_f, saln_bf);

    // P4: caq
    {
        GD6 dd; dd.n = 1;
        dd.g[0] = mkgd(saln_bf, 512, wT_caq, b_caq, caq_bf, nullptr, (int)MQ, 512, 512, 0,
                       nullptr, 0, 0, 0, 0);
        launch_multi(dd);
    }

    // P5: CA attention (bf16 out)
    {
        AttnArgs aa;
        aa.Q1 = caq_bf; aa.Q2 = caqp_bf; aa.K1 = caK; aa.K2 = cakp_bf; aa.Vt = VtCA;
        aa.mbias = mb_ca; aa.out = att_bf; aa.scale2 = 0.08838834764831845f * 1.44269504f;
        attn_ca<<<dim3(512), dim3(256), 0, stream>>>(aa);
    }

    // P6: LN2
    ln_fuse<<<dim3((unsigned)(MQ / 4)), dim3(256), 0, stream>>>(sa_ln_f, att_bf, g_ca, be_ca, ca_ln_f, caln_bf);

    // P7: FFN1
    short* mid_bf = (short*)zone2;
    {
        GD6 dd; dd.n = 1;
        dd.g[0] = mkgd(caln_bf, 512, wT_f1, b_f1, mid_bf, nullptr, (int)MQ, 2048, 512, 1,
                       nullptr, 0, 0, 0, 0);
        launch_multi(dd);
    }
    // P8: FFN2 (bf16 out)
    {
        GD6 dd; dd.n = 1;
        dd.g[0] = mkgd(mid_bf, 2048, wT_f2, b_f2, f_out, nullptr, (int)MQ, 512, 2048, 0,
                       nullptr, 0, 0, 0, 0);
        launch_multi(dd);
    }

    // P9: final LN -> d_out
    ln_fuse<<<dim3((unsigned)(MQ / 4)), dim3(256), 0, stream>>>(ca_ln_f, f_out, g_f, be_f, (float*)d_out, (short*)nullptr);
}